// Round 5
// baseline (430714.160 us; speedup 1.0000x reference)
//
#include <hip/hip_runtime.h>
#include <stdint.h>

// ---------------------------------------------------------------------------
// AnmNetwork: ADMM-like complex PSD iteration.
// B=64 batches, m=l=64, n=128, K=10 iterations.
//  * Sita = V relu(w + minv[rank]) V^H  (second eigh mathematically redundant)
//  * Lamda_new = (1 - eta/rho) Lamda + eta * V diag(relu(w+m)-w) V^H
//  * Output (T, uvec) depends only on state entering iteration K-1 -> 9 eighs.
//  * Output dtype: FLOAT32 real parts.
//  * PRNG: JAX threefry2x32, **partitionable** random_bits layout
//    (bits64[i] = cipher(key, (0, i)) — JAX >= 0.4.30 default), fold_in
//    unchanged (cipher(key, (0, it))). Round-5 single change.
// Eigensolver: fp64 parallel-order Jacobi, adaptive sweeps (8..30, exit at
// off-diag rel residual 1e-13), alternating round order per sweep.
// ---------------------------------------------------------------------------

#define BATCH 64
#define MDIM 64
#define LDIM 64
#define NDIM 128
#define NSQ (NDIM * NDIM)
#define KITER 10
#define MIN_SWEEP 8
#define MAX_SWEEP 30
#define OUT_ELEMS 266240   // 64*64*64 (T) + 64*64 (uvec), f32 real parts

// ----------------------------- threefry2x32 --------------------------------
__device__ __forceinline__ void tf_block(unsigned k0, unsigned k1,
                                         unsigned& x0, unsigned& x1) {
  unsigned k2 = k0 ^ k1 ^ 0x1BD11BDAu;
  x0 += k0; x1 += k1;
#define TF_R(r) { x0 += x1; x1 = (x1 << (r)) | (x1 >> (32 - (r))); x1 ^= x0; }
  TF_R(13) TF_R(15) TF_R(26) TF_R(6)
  x0 += k1; x1 += k2 + 1u;
  TF_R(17) TF_R(29) TF_R(16) TF_R(24)
  x0 += k2; x1 += k0 + 2u;
  TF_R(13) TF_R(15) TF_R(26) TF_R(6)
  x0 += k0; x1 += k1 + 3u;
  TF_R(17) TF_R(29) TF_R(16) TF_R(24)
  x0 += k1; x1 += k2 + 4u;
  TF_R(13) TF_R(15) TF_R(26) TF_R(6)
  x0 += k2; x1 += k0 + 5u;
#undef TF_R
}

// ------------------------------- erfinv (f64) ------------------------------
__device__ double erfinv_d(double x) {
  double w = -log1p(-x * x);
  double p;
  if (w < 6.25) {
    w -= 3.125;
    const double c[23] = {
      -3.6444120640178196996e-21, -1.685059138182016589e-19,
      1.2858480715256400167e-18,  1.115787767802518096e-17,
      -1.333171662854620906e-16,  2.0972767875968561637e-17,
      6.6376381343583238325e-15,  -4.0545662729752068639e-14,
      -8.1519341976054721522e-14, 2.6335093153082322977e-12,
      -1.2975133253453532498e-11, -5.4154120542946279317e-11,
      1.051212273321532285e-09,   -4.1126339803469836976e-09,
      -2.9070369957882005086e-08, 4.2347877827932403518e-07,
      -1.3654692000834678645e-06, -1.3882523362786468719e-05,
      1.8673420803405714802e-04,  -7.4070253416626697512e-04,
      -6.0336708714301490533e-03, 2.4015818242558961693e-01,
      1.6536545626831027356e+00};
    p = c[0];
#pragma unroll
    for (int i = 1; i < 23; ++i) p = p * w + c[i];
  } else if (w < 16.0) {
    double s = sqrt(w) - 3.25;
    const double c[19] = {
      2.2137376921775787049e-09,  9.0756561938885390979e-08,
      -2.7517406297064545428e-07, 1.8239629214389227755e-08,
      1.5027403968909827627e-06,  -4.013867526981545969e-06,
      2.9234449089955446044e-06,  1.2475304481671778723e-05,
      -4.7318229009055733981e-05, 6.8284851459573175448e-05,
      2.4031110387097893999e-05,  -3.5503752036284748449e-04,
      9.5328937973738049703e-04,  -1.6882755560235047313e-03,
      2.4914420961078508066e-03,  -3.7512085075692412107e-03,
      5.3709145535900636051e-03,  1.0052589676941592334e+00,
      3.0838856104922207635e+00};
    p = c[0];
#pragma unroll
    for (int i = 1; i < 19; ++i) p = p * s + c[i];
  } else {
    double s = sqrt(w) - 5.0;
    const double c[17] = {
      -2.7109920616438573243e-11, -2.5556418169965252055e-10,
      1.5076572693500548083e-09,  -3.7894654401267369937e-09,
      7.6157012080783393804e-09,  -1.4960026627149240478e-08,
      2.9147953450901080826e-08,  -6.7711997758452339498e-08,
      2.2900482228026654717e-07,  -9.9298272942317002539e-07,
      4.5260625972231537039e-06,  -1.9681778105531670567e-05,
      7.5995277030017761139e-05,  -2.1503011930044477347e-04,
      -1.3871931833623122026e-04, 1.0103004648645343977e+00,
      4.8499064014085844221e+00};
    p = c[0];
#pragma unroll
    for (int i = 1; i < 17; ++i) p = p * s + c[i];
  }
  double z = p * x;
  const double spi2 = 0.8862269254527580;  // sqrt(pi)/2
  double ax = fabs(x);
#pragma unroll
  for (int nr = 0; nr < 2; ++nr) {
    if (ax > 0.9375) {
      double az = fabs(z);
      double corr = (erfc(az) - (1.0 - ax)) * spi2 * exp(az * az);
      az += corr;
      z = copysign(az, x);
    } else {
      z -= (erf(z) - x) * spi2 * exp(z * z);
    }
  }
  return z;
}

// ------------------------------- kernels -----------------------------------
__global__ void zero_kernel(double* p, size_t n) {
  size_t i = (size_t)blockIdx.x * blockDim.x + threadIdx.x;
  size_t stride = (size_t)gridDim.x * blockDim.x;
  for (; i < n; i += stride) p[i] = 0.0;
}

// minv[it][b][j]: jax.random.normal(fold_in(key(42),it),(64,128),f64)
// with jax_threefry_partitionable=True (JAX >= 0.4.30 default):
//   bits64[i] = cipher(key, (hi(i)=0, lo(i)=i)); hi word = output x0.
__global__ void prng_kernel(double* minv) {
  int tid = blockIdx.x * blockDim.x + threadIdx.x;
  if (tid >= KITER * BATCH * NDIM) return;
  int it = tid / (BATCH * NDIM);
  int i = tid % (BATCH * NDIM);
  unsigned nk0 = 0u, nk1 = (unsigned)it;
  tf_block(0u, 42u, nk0, nk1);                       // fold_in (flag-independent)
  unsigned c0 = 0u, c1 = (unsigned)i;                // partitionable counter
  tf_block(nk0, nk1, c0, c1);
  unsigned long long bits = ((unsigned long long)c0 << 32) | (unsigned long long)c1;
  unsigned long long fb = (bits >> 12) | 0x3FF0000000000000ull;
  double f = __builtin_bit_cast(double, fb) - 1.0;   // [0,1)
  const double lo = __builtin_bit_cast(double, 0xBFEFFFFFFFFFFFFFull); // nextafter(-1,0)
  double uu = f * 2.0 + lo;
  if (uu < lo) uu = lo;
  minv[tid] = 1.4142135623730951 * erfinv_d(uu);
}

__global__ void compute_u_kernel(const double2* Theta, const double2* Lamda,
                                 const float* rho, const float* tau, int it,
                                 double2* u) {
  int tid = blockIdx.x * blockDim.x + threadIdx.x;
  if (tid >= BATCH * MDIM) return;
  int b = tid / MDIM, kk = tid % MDIM;
  double r = (double)rho[it], t = (double)tau[it];
  const double2* Lb = Lamda + (size_t)b * NSQ;
  const double2* Tb = Theta + (size_t)b * NSQ;
  double ar = 0.0, ai = 0.0;
  for (int i = 0; i + kk < MDIM; ++i) {
    double2 L = Lb[i * NDIM + i + kk];
    double2 Th = Tb[i * NDIM + i + kk];
    ar += L.x + r * Th.x;
    ai += L.y + r * Th.y;
  }
  if (kk == 0) ar += -(t * 0.5) * (double)MDIM;
  double s = 1.0 / ((double)(MDIM - kk) * r);
  u[b * MDIM + kk] = make_double2(ar * s, ai * s);
}

// A = Theta_pre = StackM - Lamda/r ; V = I. (A may alias Theta: element-local.)
__global__ void assemble_kernel(const double2* Theta, const double2* Lamda,
                                const double2* u, const float* Yre, const float* Yim,
                                const float* rho, const float* tau, int it,
                                double2* A, double2* V) {
  int tid = blockIdx.x * 256 + threadIdx.x;
  if (tid >= BATCH * NSQ) return;
  int b = tid / NSQ, rem = tid % NSQ, i = rem / NDIM, j = rem % NDIM;
  double r = (double)rho[it], t = (double)tau[it];
  size_t idx = (size_t)b * NSQ + rem;
  double2 L = Lamda[idx], Th = Theta[idx];
  double2 a;
  if (i < MDIM && j < MDIM) {
    int d = j - i;
    double2 uv = u[b * MDIM + (d >= 0 ? d : -d)];
    double uy = (d >= 0) ? uv.y : -uv.y;
    a.x = uv.x - L.x / r;
    a.y = uy - L.y / r;
  } else if (i < MDIM) {
    double yr = (double)Yre[(b * MDIM + i) * LDIM + (j - MDIM)];
    double yi = (double)Yim[(b * MDIM + i) * LDIM + (j - MDIM)];
    double inv = 1.0 / (1.0 + 2.0 * r);
    a.x = (yr + 2.0 * L.x + 2.0 * r * Th.x) * inv - L.x / r;
    a.y = (yi + 2.0 * L.y + 2.0 * r * Th.y) * inv - L.y / r;
  } else if (j < MDIM) {
    double yr = (double)Yre[(b * MDIM + j) * LDIM + (i - MDIM)];
    double yi = -(double)Yim[(b * MDIM + j) * LDIM + (i - MDIM)];
    double inv = 1.0 / (1.0 + 2.0 * r);
    a.x = (yr + 2.0 * L.x + 2.0 * r * Th.x) * inv - L.x / r;
    a.y = (yi + 2.0 * L.y + 2.0 * r * Th.y) * inv - L.y / r;
  } else {
    a.x = Th.x - ((i == j) ? t / (2.0 * r) : 0.0);
    a.y = Th.y;
  }
  A[idx] = a;
  V[idx] = make_double2((i == j) ? 1.0 : 0.0, 0.0);
}

__device__ __forceinline__ int pair_p(int j, int r) {
  return (j == 0) ? 0 : 1 + (j - 1 + r) % 127;
}
__device__ __forceinline__ int pair_q(int j, int r) {
  return 1 + (126 - j + r) % 127;
}

// fp64 Hermitian parallel-order Jacobi, adaptive sweeps; one block per matrix.
__global__ __launch_bounds__(256) void jacobi_kernel(double2* A, double2* V) {
  __shared__ double sc[64], sbr[64], sbi[64];
  __shared__ double red_off[256], red_tot[256];
  __shared__ int s_done;
  int b = blockIdx.x;
  double2* Ab = A + (size_t)b * NSQ;
  double2* Vb = V + (size_t)b * NSQ;
  int tid = threadIdx.x, wv = tid >> 6, ln = tid & 63;
  for (int sweep = 0; sweep < MAX_SWEEP; ++sweep) {
    for (int r0 = 0; r0 < 127; ++r0) {
      int r = (sweep & 1) ? (126 - r0) : r0;
      if (tid < 64) {
        int p = pair_p(tid, r), q = pair_q(tid, r);
        double app = Ab[p * NDIM + p].x, aqq = Ab[q * NDIM + q].x;
        double2 apq = Ab[p * NDIM + q];
        double ag2 = apq.x * apq.x + apq.y * apq.y;
        double cc = 1.0, br = 0.0, bi = 0.0;
        if (ag2 > 1e-280) {
          double ag = sqrt(ag2);
          double tau_ = (aqq - app) / (2.0 * ag);
          double tt = -copysign(1.0, tau_) / (fabs(tau_) + sqrt(1.0 + tau_ * tau_));
          cc = 1.0 / sqrt(1.0 + tt * tt);
          double tcag = tt * cc / ag;
          br = apq.x * tcag; bi = apq.y * tcag;
        }
        sc[tid] = cc; sbr[tid] = br; sbi[tid] = bi;
      }
      __syncthreads();
      // pass 1: A <- J^H A (disjoint row pairs)
      for (int jj = wv; jj < 64; jj += 4) {
        int p = pair_p(jj, r), q = pair_q(jj, r);
        double cc = sc[jj], br = sbr[jj], bi = sbi[jj];
        double2* rp = Ab + p * NDIM;
        double2* rq = Ab + q * NDIM;
        for (int col = ln; col < NDIM; col += 64) {
          double2 ap = rp[col], aq = rq[col];
          double2 np_, nq_;
          np_.x = cc * ap.x + (br * aq.x - bi * aq.y);
          np_.y = cc * ap.y + (br * aq.y + bi * aq.x);
          nq_.x = cc * aq.x - (br * ap.x + bi * ap.y);
          nq_.y = cc * aq.y - (br * ap.y - bi * ap.x);
          rp[col] = np_; rq[col] = nq_;
        }
      }
      __syncthreads();
      // pass 2: A <- A J, V <- V J (disjoint column pairs)
      {
        int p = pair_p(ln, r), q = pair_q(ln, r);
        double cc = sc[ln], br = sbr[ln], bi = sbi[ln];
        for (int row = wv; row < 256; row += 4) {
          double2* base = (row < NDIM) ? (Ab + row * NDIM) : (Vb + (row - NDIM) * NDIM);
          double2 x = base[p], y = base[q];
          double2 nx, ny;
          nx.x = cc * x.x + (br * y.x + bi * y.y);
          nx.y = cc * x.y + (br * y.y - bi * y.x);
          ny.x = cc * y.x - (br * x.x - bi * x.y);
          ny.y = cc * y.y - (br * x.y + bi * x.x);
          base[p] = nx; base[q] = ny;
        }
      }
      __syncthreads();
    }
    if (sweep >= MIN_SWEEP - 1) {
      double off = 0.0, tot = 0.0;
      for (int idx = tid; idx < NSQ; idx += 256) {
        int i = idx >> 7, j = idx & 127;
        double2 a = Ab[idx];
        double m2 = a.x * a.x + a.y * a.y;
        tot += m2;
        if (i != j) off += m2;
      }
      red_off[tid] = off; red_tot[tid] = tot;
      __syncthreads();
      for (int s = 128; s > 0; s >>= 1) {
        if (tid < s) { red_off[tid] += red_off[tid + s]; red_tot[tid] += red_tot[tid + s]; }
        __syncthreads();
      }
      if (tid == 0) s_done = (red_off[0] <= 1e-26 * red_tot[0]) ? 1 : 0;
      __syncthreads();
      if (s_done) break;
    }
  }
}

// ranks of eigenvalues -> d1 = relu(w + minv[rank]), d2 = d1 - w
__global__ void rankd_kernel(const double2* A, const double* minv, int it,
                             double* d1, double* d2) {
  __shared__ double w[NDIM];
  int b = blockIdx.x, j = threadIdx.x;
  w[j] = A[(size_t)b * NSQ + j * NDIM + j].x;
  __syncthreads();
  double wj = w[j];
  int rank = 0;
  for (int k = 0; k < NDIM; ++k) {
    double wk = w[k];
    rank += (wk < wj) || (wk == wj && k < j);
  }
  double mv = minv[(it * BATCH + b) * NDIM + rank];
  double v = wj + mv;
  if (v < 0.0) v = 0.0;
  d1[b * NDIM + j] = v;
  d2[b * NDIM + j] = v - wj;
}

// Theta = V diag(d1) V^H ; Lamda = (1-e/r) Lamda + e * V diag(d2) V^H
__global__ __launch_bounds__(256) void update_kernel(
    const double2* V, const double* d1, const double* d2,
    const float* rho, const float* eta, int it,
    double2* Theta, double2* Lamda) {
  __shared__ double2 Vi[32][33];
  __shared__ double2 Vk[32][33];
  __shared__ double s1[32], s2[32];
  int blk = blockIdx.x;
  int b = blk >> 4, tile = blk & 15, ti = tile >> 2, tk = tile & 3;
  int tid = threadIdx.x;
  int lk = tid & 31, lig = tid >> 5;
  double r = (double)rho[it], e = (double)eta[it];
  double a1x[4] = {0, 0, 0, 0}, a1y[4] = {0, 0, 0, 0};
  double a2x[4] = {0, 0, 0, 0}, a2y[4] = {0, 0, 0, 0};
  const double2* Vb = V + (size_t)b * NSQ;
  for (int jc = 0; jc < 4; ++jc) {
    for (int e2 = tid; e2 < 1024; e2 += 256) {
      int rr = e2 >> 5, cc2 = e2 & 31;
      Vi[rr][cc2] = Vb[(ti * 32 + rr) * NDIM + jc * 32 + cc2];
      Vk[rr][cc2] = Vb[(tk * 32 + rr) * NDIM + jc * 32 + cc2];
    }
    if (tid < 32) {
      s1[tid] = d1[b * NDIM + jc * 32 + tid];
      s2[tid] = d2[b * NDIM + jc * 32 + tid];
    }
    __syncthreads();
#pragma unroll
    for (int uo = 0; uo < 4; ++uo) {
      int li = lig + uo * 8;
      double ax = a1x[uo], ay = a1y[uo], bx = a2x[uo], by = a2y[uo];
      for (int j = 0; j < 32; ++j) {
        double2 va = Vi[li][j], vb = Vk[lk][j];
        double pr = va.x * vb.x + va.y * vb.y;
        double pi = va.y * vb.x - va.x * vb.y;
        ax += s1[j] * pr; ay += s1[j] * pi;
        bx += s2[j] * pr; by += s2[j] * pi;
      }
      a1x[uo] = ax; a1y[uo] = ay; a2x[uo] = bx; a2y[uo] = by;
    }
    __syncthreads();
  }
  double lf = 1.0 - e / r;
#pragma unroll
  for (int uo = 0; uo < 4; ++uo) {
    int gi = ti * 32 + lig + uo * 8, gk = tk * 32 + lk;
    size_t idx = (size_t)b * NSQ + gi * NDIM + gk;
    Theta[idx] = make_double2(a1x[uo], a1y[uo]);
    double2 Lold = Lamda[idx];
    Lamda[idx] = make_double2(lf * Lold.x + e * a2x[uo], lf * Lold.y + e * a2y[uo]);
  }
}

// OUTPUT (float32 real parts): T[i][j] = u[|i-j|].re ; uvec.re = u.re
__global__ void writeout_kernel(const double2* u, float* out) {
  int tid = blockIdx.x * 256 + threadIdx.x;
  if (tid >= OUT_ELEMS) return;
  double re;
  if (tid < BATCH * MDIM * MDIM) {
    int b = tid >> 12, rem = tid & 4095, i = rem >> 6, j = rem & 63;
    int d = j - i;
    re = u[b * MDIM + (d >= 0 ? d : -d)].x;
  } else {
    int k2 = tid - BATCH * MDIM * MDIM;
    int b = k2 >> 6, kk = k2 & 63;
    re = u[b * MDIM + kk].x;
  }
  out[tid] = (float)re;
}

// ------------------------------- launch ------------------------------------
extern "C" void kernel_launch(void* const* d_in, const int* in_sizes, int n_in,
                              void* d_out, int out_size, void* d_ws, size_t ws_size,
                              hipStream_t stream) {
  const float* Yre = (const float*)d_in[0];
  const float* Yim = (const float*)d_in[1];
  const float* rho = (const float*)d_in[2];
  const float* tau = (const float*)d_in[3];
  const float* eta = (const float*)d_in[4];
  float* out = (float*)d_out;

  char* ws = (char*)d_ws;
  size_t off = 0;
  auto take = [&](size_t bytes) -> char* {
    char* p = ws + off;
    off += (bytes + 255) & ~(size_t)255;
    return p;
  };
  double2* u     = (double2*)take((size_t)BATCH * MDIM * sizeof(double2));
  double*  minv  = (double*)take((size_t)KITER * BATCH * NDIM * sizeof(double));
  double*  d1    = (double*)take((size_t)BATCH * NDIM * sizeof(double));
  double*  d2    = (double*)take((size_t)BATCH * NDIM * sizeof(double));
  double2* Lamda = (double2*)take((size_t)BATCH * NSQ * sizeof(double2));
  double2* Theta = (double2*)take((size_t)BATCH * NSQ * sizeof(double2));
  double2* V     = (double2*)take((size_t)BATCH * NSQ * sizeof(double2));
  double2* A     = Theta;  // alias: assemble element-local; update rewrites
  (void)in_sizes; (void)n_in; (void)ws_size; (void)out_size;

  zero_kernel<<<2048, 256, 0, stream>>>((double*)Theta, (size_t)BATCH * NSQ * 2);
  zero_kernel<<<2048, 256, 0, stream>>>((double*)Lamda, (size_t)BATCH * NSQ * 2);
  prng_kernel<<<(KITER * BATCH * NDIM + 255) / 256, 256, 0, stream>>>(minv);

  for (int it = 0; it < KITER - 1; ++it) {
    compute_u_kernel<<<16, 256, 0, stream>>>(Theta, Lamda, rho, tau, it, u);
    assemble_kernel<<<BATCH * NSQ / 256, 256, 0, stream>>>(Theta, Lamda, u, Yre, Yim,
                                                           rho, tau, it, A, V);
    jacobi_kernel<<<BATCH, 256, 0, stream>>>(A, V);
    rankd_kernel<<<BATCH, NDIM, 0, stream>>>(A, minv, it, d1, d2);
    update_kernel<<<BATCH * 16, 256, 0, stream>>>(V, d1, d2, rho, eta, it, Theta, Lamda);
  }
  compute_u_kernel<<<16, 256, 0, stream>>>(Theta, Lamda, rho, tau, KITER - 1, u);
  writeout_kernel<<<(OUT_ELEMS + 255) / 256, 256, 0, stream>>>(u, out);
}

// Round 6
// 82604.364 us; speedup vs baseline: 5.2142x; 5.2142x over previous
//
#include <hip/hip_runtime.h>
#include <stdint.h>

// ---------------------------------------------------------------------------
// AnmNetwork: ADMM-like complex PSD iteration. B=64, m=l=64, n=128, K=10.
//  * Sita = V relu(w + minv[rank]) V^H  (second eigh mathematically redundant)
//  * Lamda_new = (1 - eta/rho) Lamda + eta * V diag(relu(w+m)-w) V^H
//  * Output depends only on state entering iteration K-1 -> 9 eigh rounds.
//  * PRNG: JAX threefry2x32 partitionable counters (verified bit-exact R5).
// R6 perf rewrite of the eigensolver (95% of runtime):
//  * fp32 Jacobi: A in LDS (128x129 float2 = 132 KB dynamic), V fp32 in
//    global (L2-resident), 1024 threads/block, adaptive sweeps (cap 16,
//    exit off^2 <= 1e-10 * tot^2 checked from sweep 5).
//  * Tolerance analysis: fp32 eigenvector error ~1e-4, rank-swap prob ~1e-9;
//    output threshold 0.2475, fully-decorrelated minv only moved it 0.56.
//  * State (Theta/Lamda), PRNG, u, writeout stay fp64.
// ---------------------------------------------------------------------------

#define BATCH 64
#define MDIM 64
#define LDIM 64
#define NDIM 128
#define NSQ (NDIM * NDIM)
#define KITER 10
#define MAXS 16            // fp32 cyclic Jacobi at n=128 converges in ~6-9
#define RS 129             // padded LDS row stride (float2 units)
#define JAC_LDS_BYTES (NDIM * RS * (int)sizeof(float2))   // 132,096 B
#define OUT_ELEMS 266240   // 64*64*64 (T) + 64*64 (uvec), f32 real parts

// ----------------------------- threefry2x32 --------------------------------
__device__ __forceinline__ void tf_block(unsigned k0, unsigned k1,
                                         unsigned& x0, unsigned& x1) {
  unsigned k2 = k0 ^ k1 ^ 0x1BD11BDAu;
  x0 += k0; x1 += k1;
#define TF_R(r) { x0 += x1; x1 = (x1 << (r)) | (x1 >> (32 - (r))); x1 ^= x0; }
  TF_R(13) TF_R(15) TF_R(26) TF_R(6)
  x0 += k1; x1 += k2 + 1u;
  TF_R(17) TF_R(29) TF_R(16) TF_R(24)
  x0 += k2; x1 += k0 + 2u;
  TF_R(13) TF_R(15) TF_R(26) TF_R(6)
  x0 += k0; x1 += k1 + 3u;
  TF_R(17) TF_R(29) TF_R(16) TF_R(24)
  x0 += k1; x1 += k2 + 4u;
  TF_R(13) TF_R(15) TF_R(26) TF_R(6)
  x0 += k2; x1 += k0 + 5u;
#undef TF_R
}

// ------------------------------- erfinv (f64) ------------------------------
__device__ double erfinv_d(double x) {
  double w = -log1p(-x * x);
  double p;
  if (w < 6.25) {
    w -= 3.125;
    const double c[23] = {
      -3.6444120640178196996e-21, -1.685059138182016589e-19,
      1.2858480715256400167e-18,  1.115787767802518096e-17,
      -1.333171662854620906e-16,  2.0972767875968561637e-17,
      6.6376381343583238325e-15,  -4.0545662729752068639e-14,
      -8.1519341976054721522e-14, 2.6335093153082322977e-12,
      -1.2975133253453532498e-11, -5.4154120542946279317e-11,
      1.051212273321532285e-09,   -4.1126339803469836976e-09,
      -2.9070369957882005086e-08, 4.2347877827932403518e-07,
      -1.3654692000834678645e-06, -1.3882523362786468719e-05,
      1.8673420803405714802e-04,  -7.4070253416626697512e-04,
      -6.0336708714301490533e-03, 2.4015818242558961693e-01,
      1.6536545626831027356e+00};
    p = c[0];
#pragma unroll
    for (int i = 1; i < 23; ++i) p = p * w + c[i];
  } else if (w < 16.0) {
    double s = sqrt(w) - 3.25;
    const double c[19] = {
      2.2137376921775787049e-09,  9.0756561938885390979e-08,
      -2.7517406297064545428e-07, 1.8239629214389227755e-08,
      1.5027403968909827627e-06,  -4.013867526981545969e-06,
      2.9234449089955446044e-06,  1.2475304481671778723e-05,
      -4.7318229009055733981e-05, 6.8284851459573175448e-05,
      2.4031110387097893999e-05,  -3.5503752036284748449e-04,
      9.5328937973738049703e-04,  -1.6882755560235047313e-03,
      2.4914420961078508066e-03,  -3.7512085075692412107e-03,
      5.3709145535900636051e-03,  1.0052589676941592334e+00,
      3.0838856104922207635e+00};
    p = c[0];
#pragma unroll
    for (int i = 1; i < 19; ++i) p = p * s + c[i];
  } else {
    double s = sqrt(w) - 5.0;
    const double c[17] = {
      -2.7109920616438573243e-11, -2.5556418169965252055e-10,
      1.5076572693500548083e-09,  -3.7894654401267369937e-09,
      7.6157012080783393804e-09,  -1.4960026627149240478e-08,
      2.9147953450901080826e-08,  -6.7711997758452339498e-08,
      2.2900482228026654717e-07,  -9.9298272942317002539e-07,
      4.5260625972231537039e-06,  -1.9681778105531670567e-05,
      7.5995277030017761139e-05,  -2.1503011930044477347e-04,
      -1.3871931833623122026e-04, 1.0103004648645343977e+00,
      4.8499064014085844221e+00};
    p = c[0];
#pragma unroll
    for (int i = 1; i < 17; ++i) p = p * s + c[i];
  }
  double z = p * x;
  const double spi2 = 0.8862269254527580;  // sqrt(pi)/2
  double ax = fabs(x);
#pragma unroll
  for (int nr = 0; nr < 2; ++nr) {
    if (ax > 0.9375) {
      double az = fabs(z);
      double corr = (erfc(az) - (1.0 - ax)) * spi2 * exp(az * az);
      az += corr;
      z = copysign(az, x);
    } else {
      z -= (erf(z) - x) * spi2 * exp(z * z);
    }
  }
  return z;
}

// ------------------------------- kernels -----------------------------------
__global__ void zero_kernel(double* p, size_t n) {
  size_t i = (size_t)blockIdx.x * blockDim.x + threadIdx.x;
  size_t stride = (size_t)gridDim.x * blockDim.x;
  for (; i < n; i += stride) p[i] = 0.0;
}

// minv[it][b][j]: jax.random.normal(fold_in(key(42),it),(64,128),f64),
// partitionable counters: bits64[i] = cipher(key, (0, i)).
__global__ void prng_kernel(double* minv) {
  int tid = blockIdx.x * blockDim.x + threadIdx.x;
  if (tid >= KITER * BATCH * NDIM) return;
  int it = tid / (BATCH * NDIM);
  int i = tid % (BATCH * NDIM);
  unsigned nk0 = 0u, nk1 = (unsigned)it;
  tf_block(0u, 42u, nk0, nk1);                       // fold_in
  unsigned c0 = 0u, c1 = (unsigned)i;
  tf_block(nk0, nk1, c0, c1);
  unsigned long long bits = ((unsigned long long)c0 << 32) | (unsigned long long)c1;
  unsigned long long fb = (bits >> 12) | 0x3FF0000000000000ull;
  double f = __builtin_bit_cast(double, fb) - 1.0;   // [0,1)
  const double lo = __builtin_bit_cast(double, 0xBFEFFFFFFFFFFFFFull);
  double uu = f * 2.0 + lo;
  if (uu < lo) uu = lo;
  minv[tid] = 1.4142135623730951 * erfinv_d(uu);
}

__global__ void compute_u_kernel(const double2* Theta, const double2* Lamda,
                                 const float* rho, const float* tau, int it,
                                 double2* u) {
  int tid = blockIdx.x * blockDim.x + threadIdx.x;
  if (tid >= BATCH * MDIM) return;
  int b = tid / MDIM, kk = tid % MDIM;
  double r = (double)rho[it], t = (double)tau[it];
  const double2* Lb = Lamda + (size_t)b * NSQ;
  const double2* Tb = Theta + (size_t)b * NSQ;
  double ar = 0.0, ai = 0.0;
  for (int i = 0; i + kk < MDIM; ++i) {
    double2 L = Lb[i * NDIM + i + kk];
    double2 Th = Tb[i * NDIM + i + kk];
    ar += L.x + r * Th.x;
    ai += L.y + r * Th.y;
  }
  if (kk == 0) ar += -(t * 0.5) * (double)MDIM;
  double s = 1.0 / ((double)(MDIM - kk) * r);
  u[b * MDIM + kk] = make_double2(ar * s, ai * s);
}

// A32 = fp32(StackM - Lamda/r) ; V32 = I
__global__ void assemble_kernel(const double2* Theta, const double2* Lamda,
                                const double2* u, const float* Yre, const float* Yim,
                                const float* rho, const float* tau, int it,
                                float2* A32, float2* V32) {
  int tid = blockIdx.x * 256 + threadIdx.x;
  if (tid >= BATCH * NSQ) return;
  int b = tid / NSQ, rem = tid % NSQ, i = rem / NDIM, j = rem % NDIM;
  double r = (double)rho[it], t = (double)tau[it];
  size_t idx = (size_t)b * NSQ + rem;
  double2 L = Lamda[idx], Th = Theta[idx];
  double axr, axi;
  if (i < MDIM && j < MDIM) {
    int d = j - i;
    double2 uv = u[b * MDIM + (d >= 0 ? d : -d)];
    double uy = (d >= 0) ? uv.y : -uv.y;
    axr = uv.x - L.x / r;
    axi = uy - L.y / r;
  } else if (i < MDIM) {
    double yr = (double)Yre[(b * MDIM + i) * LDIM + (j - MDIM)];
    double yi = (double)Yim[(b * MDIM + i) * LDIM + (j - MDIM)];
    double inv = 1.0 / (1.0 + 2.0 * r);
    axr = (yr + 2.0 * L.x + 2.0 * r * Th.x) * inv - L.x / r;
    axi = (yi + 2.0 * L.y + 2.0 * r * Th.y) * inv - L.y / r;
  } else if (j < MDIM) {
    double yr = (double)Yre[(b * MDIM + j) * LDIM + (i - MDIM)];
    double yi = -(double)Yim[(b * MDIM + j) * LDIM + (i - MDIM)];
    double inv = 1.0 / (1.0 + 2.0 * r);
    axr = (yr + 2.0 * L.x + 2.0 * r * Th.x) * inv - L.x / r;
    axi = (yi + 2.0 * L.y + 2.0 * r * Th.y) * inv - L.y / r;
  } else {
    axr = Th.x - ((i == j) ? t / (2.0 * r) : 0.0);
    axi = Th.y;
  }
  A32[idx] = make_float2((float)axr, (float)axi);
  V32[idx] = make_float2((i == j) ? 1.0f : 0.0f, 0.0f);
}

__device__ __forceinline__ int pair_p(int j, int r) {
  return (j == 0) ? 0 : 1 + (j - 1 + r) % 127;
}
__device__ __forceinline__ int pair_q(int j, int r) {
  return 1 + (126 - j + r) % 127;
}

// fp32 Hermitian parallel-order Jacobi. A in LDS (padded), V in global (L2).
// One block of 1024 threads per matrix. Writes eigenvalues to wout.
__global__ __launch_bounds__(1024) void jacobi32_kernel(const float2* __restrict__ A,
                                                        float2* __restrict__ V,
                                                        float* __restrict__ wout) {
  extern __shared__ float2 sA[];               // 128 x 129 float2 (132 KB)
  __shared__ float sc[64], sbr[64], sbi[64];
  __shared__ float s_off[16], s_tot[16];
  __shared__ int s_done;
  int b = blockIdx.x, tid = threadIdx.x;
  const float2* Ag = A + (size_t)b * NSQ;
  float2* Vg = V + (size_t)b * NSQ;
  for (int i = tid; i < NSQ; i += 1024)
    sA[(i >> 7) * RS + (i & 127)] = Ag[i];
  __syncthreads();
  for (int sweep = 0; sweep < MAXS; ++sweep) {
    for (int r0 = 0; r0 < 127; ++r0) {
      int r = (sweep & 1) ? (126 - r0) : r0;
      if (tid < 64) {
        int p = pair_p(tid, r), q = pair_q(tid, r);
        float app = sA[p * RS + p].x, aqq = sA[q * RS + q].x;
        float2 apq = sA[p * RS + q];
        float ag2 = apq.x * apq.x + apq.y * apq.y;
        float cc = 1.0f, br = 0.0f, bi = 0.0f;
        if (ag2 > 1e-24f) {
          float ag = sqrtf(ag2);
          float ta = (aqq - app) / (2.0f * ag);
          float tt = -copysignf(1.0f, ta) / (fabsf(ta) + sqrtf(1.0f + ta * ta));
          cc = 1.0f / sqrtf(1.0f + tt * tt);
          float tcag = tt * cc / ag;
          br = apq.x * tcag; bi = apq.y * tcag;
        }
        sc[tid] = cc; sbr[tid] = br; sbi[tid] = bi;
      }
      __syncthreads();
      // pass 1: A <- J^H A  (items: pair j = i>>7, col = i&127)
      {
        int col = tid & 127;
#pragma unroll
        for (int k = 0; k < 8; ++k) {
          int j = (tid >> 7) + k * 8;
          int p = pair_p(j, r), q = pair_q(j, r);
          float cc = sc[j], br = sbr[j], bi = sbi[j];
          float2 ap = sA[p * RS + col], aq = sA[q * RS + col];
          float2 np_, nq_;
          np_.x = cc * ap.x + (br * aq.x - bi * aq.y);
          np_.y = cc * ap.y + (br * aq.y + bi * aq.x);
          nq_.x = cc * aq.x - (br * ap.x + bi * ap.y);
          nq_.y = cc * aq.y - (br * ap.y - bi * ap.x);
          sA[p * RS + col] = np_; sA[q * RS + col] = nq_;
        }
      }
      __syncthreads();
      // pass 2: A <- A J (cols) + V <- V J  (items: pair j = i&63, row = i>>6)
      {
        int j = tid & 63;
        int p = pair_p(j, r), q = pair_q(j, r);
        float cc = sc[j], br = sbr[j], bi = sbi[j];
#pragma unroll
        for (int k = 0; k < 8; ++k) {
          int row = (tid >> 6) + k * 16;
          float2 x = sA[row * RS + p], y = sA[row * RS + q];
          float2 nx, ny;
          nx.x = cc * x.x + (br * y.x + bi * y.y);
          nx.y = cc * x.y + (br * y.y - bi * y.x);
          ny.x = cc * y.x - (br * x.x - bi * x.y);
          ny.y = cc * y.y - (br * x.y + bi * x.x);
          sA[row * RS + p] = nx; sA[row * RS + q] = ny;
          float2 vx = Vg[row * NDIM + p], vy = Vg[row * NDIM + q];
          float2 wx, wy;
          wx.x = cc * vx.x + (br * vy.x + bi * vy.y);
          wx.y = cc * vx.y + (br * vy.y - bi * vy.x);
          wy.x = cc * vy.x - (br * vx.x - bi * vx.y);
          wy.y = cc * vy.y - (br * vx.y + bi * vx.x);
          Vg[row * NDIM + p] = wx; Vg[row * NDIM + q] = wy;
        }
      }
      __syncthreads();
    }
    if (sweep >= 4) {   // convergence: off^2 <= 1e-10 * tot^2
      float off = 0.0f, tot = 0.0f;
      for (int i = tid; i < NSQ; i += 1024) {
        int rr = i >> 7, cl = i & 127;
        float2 a = sA[rr * RS + cl];
        float m2 = a.x * a.x + a.y * a.y;
        tot += m2;
        if (rr != cl) off += m2;
      }
      for (int s = 32; s > 0; s >>= 1) {
        off += __shfl_down(off, s);
        tot += __shfl_down(tot, s);
      }
      if ((tid & 63) == 0) { s_off[tid >> 6] = off; s_tot[tid >> 6] = tot; }
      __syncthreads();
      if (tid == 0) {
        float o = 0.0f, t2 = 0.0f;
        for (int z = 0; z < 16; ++z) { o += s_off[z]; t2 += s_tot[z]; }
        s_done = (o <= 1e-10f * t2) ? 1 : 0;
      }
      __syncthreads();
      if (s_done) break;
    }
  }
  if (tid < NDIM) wout[b * NDIM + tid] = sA[tid * RS + tid].x;
}

// ranks of eigenvalues -> d1 = relu(w + minv[rank]), d2 = d1 - w
__global__ void rankd_kernel(const float* w_in, const double* minv, int it,
                             double* d1, double* d2) {
  __shared__ float w[NDIM];
  int b = blockIdx.x, j = threadIdx.x;
  w[j] = w_in[b * NDIM + j];
  __syncthreads();
  float wj = w[j];
  int rank = 0;
  for (int k = 0; k < NDIM; ++k) {
    float wk = w[k];
    rank += (wk < wj) || (wk == wj && k < j);
  }
  double mv = minv[(it * BATCH + b) * NDIM + rank];
  double v = (double)wj + mv;
  if (v < 0.0) v = 0.0;
  d1[b * NDIM + j] = v;
  d2[b * NDIM + j] = v - (double)wj;
}

// Theta = V diag(d1) V^H ; Lamda = (1-e/r) Lamda + e * V diag(d2) V^H
// V is fp32; products fp32, accumulation fp64.
__global__ __launch_bounds__(256) void update_kernel(
    const float2* V, const double* d1, const double* d2,
    const float* rho, const float* eta, int it,
    double2* Theta, double2* Lamda) {
  __shared__ float2 Vi[32][33];
  __shared__ float2 Vk[32][33];
  __shared__ double s1[32], s2[32];
  int blk = blockIdx.x;
  int b = blk >> 4, tile = blk & 15, ti = tile >> 2, tk = tile & 3;
  int tid = threadIdx.x;
  int lk = tid & 31, lig = tid >> 5;
  double r = (double)rho[it], e = (double)eta[it];
  double a1x[4] = {0, 0, 0, 0}, a1y[4] = {0, 0, 0, 0};
  double a2x[4] = {0, 0, 0, 0}, a2y[4] = {0, 0, 0, 0};
  const float2* Vb = V + (size_t)b * NSQ;
  for (int jc = 0; jc < 4; ++jc) {
    for (int e2 = tid; e2 < 1024; e2 += 256) {
      int rr = e2 >> 5, cc2 = e2 & 31;
      Vi[rr][cc2] = Vb[(ti * 32 + rr) * NDIM + jc * 32 + cc2];
      Vk[rr][cc2] = Vb[(tk * 32 + rr) * NDIM + jc * 32 + cc2];
    }
    if (tid < 32) {
      s1[tid] = d1[b * NDIM + jc * 32 + tid];
      s2[tid] = d2[b * NDIM + jc * 32 + tid];
    }
    __syncthreads();
#pragma unroll
    for (int uo = 0; uo < 4; ++uo) {
      int li = lig + uo * 8;
      double ax = a1x[uo], ay = a1y[uo], bx = a2x[uo], by = a2y[uo];
      for (int j = 0; j < 32; ++j) {
        float2 va = Vi[li][j], vb = Vk[lk][j];
        double pr = (double)(va.x * vb.x + va.y * vb.y);
        double pi = (double)(va.y * vb.x - va.x * vb.y);
        ax += s1[j] * pr; ay += s1[j] * pi;
        bx += s2[j] * pr; by += s2[j] * pi;
      }
      a1x[uo] = ax; a1y[uo] = ay; a2x[uo] = bx; a2y[uo] = by;
    }
    __syncthreads();
  }
  double lf = 1.0 - e / r;
#pragma unroll
  for (int uo = 0; uo < 4; ++uo) {
    int gi = ti * 32 + lig + uo * 8, gk = tk * 32 + lk;
    size_t idx = (size_t)b * NSQ + gi * NDIM + gk;
    Theta[idx] = make_double2(a1x[uo], a1y[uo]);
    double2 Lold = Lamda[idx];
    Lamda[idx] = make_double2(lf * Lold.x + e * a2x[uo], lf * Lold.y + e * a2y[uo]);
  }
}

// OUTPUT (float32 real parts): T[i][j] = u[|i-j|].re ; uvec.re = u.re
__global__ void writeout_kernel(const double2* u, float* out) {
  int tid = blockIdx.x * 256 + threadIdx.x;
  if (tid >= OUT_ELEMS) return;
  double re;
  if (tid < BATCH * MDIM * MDIM) {
    int b = tid >> 12, rem = tid & 4095, i = rem >> 6, j = rem & 63;
    int d = j - i;
    re = u[b * MDIM + (d >= 0 ? d : -d)].x;
  } else {
    int k2 = tid - BATCH * MDIM * MDIM;
    int b = k2 >> 6, kk = k2 & 63;
    re = u[b * MDIM + kk].x;
  }
  out[tid] = (float)re;
}

// ------------------------------- launch ------------------------------------
extern "C" void kernel_launch(void* const* d_in, const int* in_sizes, int n_in,
                              void* d_out, int out_size, void* d_ws, size_t ws_size,
                              hipStream_t stream) {
  const float* Yre = (const float*)d_in[0];
  const float* Yim = (const float*)d_in[1];
  const float* rho = (const float*)d_in[2];
  const float* tau = (const float*)d_in[3];
  const float* eta = (const float*)d_in[4];
  float* out = (float*)d_out;

  char* ws = (char*)d_ws;
  size_t off = 0;
  auto take = [&](size_t bytes) -> char* {
    char* p = ws + off;
    off += (bytes + 255) & ~(size_t)255;
    return p;
  };
  double2* u     = (double2*)take((size_t)BATCH * MDIM * sizeof(double2));
  double*  minv  = (double*)take((size_t)KITER * BATCH * NDIM * sizeof(double));
  double*  d1    = (double*)take((size_t)BATCH * NDIM * sizeof(double));
  double*  d2    = (double*)take((size_t)BATCH * NDIM * sizeof(double));
  float*   wbuf  = (float*)take((size_t)BATCH * NDIM * sizeof(float));
  double2* Lamda = (double2*)take((size_t)BATCH * NSQ * sizeof(double2));  // 16.8 MB
  double2* Theta = (double2*)take((size_t)BATCH * NSQ * sizeof(double2));  // 16.8 MB
  float2*  A32   = (float2*)take((size_t)BATCH * NSQ * sizeof(float2));    //  8.4 MB
  float2*  V32   = (float2*)take((size_t)BATCH * NSQ * sizeof(float2));    //  8.4 MB
  (void)in_sizes; (void)n_in; (void)ws_size; (void)out_size;  // ~51 MB total

  // Allow 132 KB dynamic LDS (idempotent; legal outside stream ops).
  hipFuncSetAttribute((const void*)jacobi32_kernel,
                      hipFuncAttributeMaxDynamicSharedMemorySize, JAC_LDS_BYTES);

  zero_kernel<<<2048, 256, 0, stream>>>((double*)Theta, (size_t)BATCH * NSQ * 2);
  zero_kernel<<<2048, 256, 0, stream>>>((double*)Lamda, (size_t)BATCH * NSQ * 2);
  prng_kernel<<<(KITER * BATCH * NDIM + 255) / 256, 256, 0, stream>>>(minv);

  for (int it = 0; it < KITER - 1; ++it) {
    compute_u_kernel<<<16, 256, 0, stream>>>(Theta, Lamda, rho, tau, it, u);
    assemble_kernel<<<BATCH * NSQ / 256, 256, 0, stream>>>(Theta, Lamda, u, Yre, Yim,
                                                           rho, tau, it, A32, V32);
    jacobi32_kernel<<<BATCH, 1024, JAC_LDS_BYTES, stream>>>(A32, V32, wbuf);
    rankd_kernel<<<BATCH, NDIM, 0, stream>>>(wbuf, minv, it, d1, d2);
    update_kernel<<<BATCH * 16, 256, 0, stream>>>(V32, d1, d2, rho, eta, it, Theta, Lamda);
  }
  compute_u_kernel<<<16, 256, 0, stream>>>(Theta, Lamda, rho, tau, KITER - 1, u);
  writeout_kernel<<<(OUT_ELEMS + 255) / 256, 256, 0, stream>>>(u, out);
}

// Round 7
// 81083.881 us; speedup vs baseline: 5.3120x; 1.0188x over previous
//
#include <hip/hip_runtime.h>
#include <stdint.h>

// ---------------------------------------------------------------------------
// AnmNetwork: ADMM-like complex PSD iteration. B=64, m=l=64, n=128, K=10.
//  * Sita = V relu(w + minv[rank]) V^H  (second eigh mathematically redundant)
//  * Lamda_new = (1 - eta/rho) Lamda + eta * V diag(relu(w+m)-w) V^H
//  * Output depends only on state entering iteration K-1 -> 9 eigh rounds.
//  * PRNG: JAX threefry2x32 partitionable counters (bit-exact, R5).
// R7 (jacobi = 95% of runtime, was bank-conflict + gather bound):
//  * LDS A as SoA re/im fp32 planes, stride 129 floats -> pass2's distinct-p
//    access lands (row*129+p)%32, ~2 lanes/bank = free (was float2 -> even
//    banks only, >=4-way, 3.6e7 SQ_LDS_BANK_CONFLICT).
//  * Eigenvectors stored TRANSPOSED (U = V^T) in global: column rotations
//    become coalesced row rotations, merged into pass 1 (same params).
//  * pair indices precomputed per round; rankd fused into jacobi epilogue.
//  * update_kernel: coalesced U tile loads, SoA tiles (conflict-free).
// State (Theta/Lamda), PRNG, u, writeout stay fp64.
// ---------------------------------------------------------------------------

#define BATCH 64
#define MDIM 64
#define LDIM 64
#define NDIM 128
#define NSQ (NDIM * NDIM)
#define KITER 10
#define MAXS 16
#define RS 129                                  // LDS row stride (floats)
#define JAC_LDS_BYTES (2 * NDIM * RS * (int)sizeof(float))   // 132,096 B
#define OUT_ELEMS 266240   // 64*64*64 (T) + 64*64 (uvec), f32 real parts

// ----------------------------- threefry2x32 --------------------------------
__device__ __forceinline__ void tf_block(unsigned k0, unsigned k1,
                                         unsigned& x0, unsigned& x1) {
  unsigned k2 = k0 ^ k1 ^ 0x1BD11BDAu;
  x0 += k0; x1 += k1;
#define TF_R(r) { x0 += x1; x1 = (x1 << (r)) | (x1 >> (32 - (r))); x1 ^= x0; }
  TF_R(13) TF_R(15) TF_R(26) TF_R(6)
  x0 += k1; x1 += k2 + 1u;
  TF_R(17) TF_R(29) TF_R(16) TF_R(24)
  x0 += k2; x1 += k0 + 2u;
  TF_R(13) TF_R(15) TF_R(26) TF_R(6)
  x0 += k0; x1 += k1 + 3u;
  TF_R(17) TF_R(29) TF_R(16) TF_R(24)
  x0 += k1; x1 += k2 + 4u;
  TF_R(13) TF_R(15) TF_R(26) TF_R(6)
  x0 += k2; x1 += k0 + 5u;
#undef TF_R
}

// ------------------------------- erfinv (f64) ------------------------------
__device__ double erfinv_d(double x) {
  double w = -log1p(-x * x);
  double p;
  if (w < 6.25) {
    w -= 3.125;
    const double c[23] = {
      -3.6444120640178196996e-21, -1.685059138182016589e-19,
      1.2858480715256400167e-18,  1.115787767802518096e-17,
      -1.333171662854620906e-16,  2.0972767875968561637e-17,
      6.6376381343583238325e-15,  -4.0545662729752068639e-14,
      -8.1519341976054721522e-14, 2.6335093153082322977e-12,
      -1.2975133253453532498e-11, -5.4154120542946279317e-11,
      1.051212273321532285e-09,   -4.1126339803469836976e-09,
      -2.9070369957882005086e-08, 4.2347877827932403518e-07,
      -1.3654692000834678645e-06, -1.3882523362786468719e-05,
      1.8673420803405714802e-04,  -7.4070253416626697512e-04,
      -6.0336708714301490533e-03, 2.4015818242558961693e-01,
      1.6536545626831027356e+00};
    p = c[0];
#pragma unroll
    for (int i = 1; i < 23; ++i) p = p * w + c[i];
  } else if (w < 16.0) {
    double s = sqrt(w) - 3.25;
    const double c[19] = {
      2.2137376921775787049e-09,  9.0756561938885390979e-08,
      -2.7517406297064545428e-07, 1.8239629214389227755e-08,
      1.5027403968909827627e-06,  -4.013867526981545969e-06,
      2.9234449089955446044e-06,  1.2475304481671778723e-05,
      -4.7318229009055733981e-05, 6.8284851459573175448e-05,
      2.4031110387097893999e-05,  -3.5503752036284748449e-04,
      9.5328937973738049703e-04,  -1.6882755560235047313e-03,
      2.4914420961078508066e-03,  -3.7512085075692412107e-03,
      5.3709145535900636051e-03,  1.0052589676941592334e+00,
      3.0838856104922207635e+00};
    p = c[0];
#pragma unroll
    for (int i = 1; i < 19; ++i) p = p * s + c[i];
  } else {
    double s = sqrt(w) - 5.0;
    const double c[17] = {
      -2.7109920616438573243e-11, -2.5556418169965252055e-10,
      1.5076572693500548083e-09,  -3.7894654401267369937e-09,
      7.6157012080783393804e-09,  -1.4960026627149240478e-08,
      2.9147953450901080826e-08,  -6.7711997758452339498e-08,
      2.2900482228026654717e-07,  -9.9298272942317002539e-07,
      4.5260625972231537039e-06,  -1.9681778105531670567e-05,
      7.5995277030017761139e-05,  -2.1503011930044477347e-04,
      -1.3871931833623122026e-04, 1.0103004648645343977e+00,
      4.8499064014085844221e+00};
    p = c[0];
#pragma unroll
    for (int i = 1; i < 17; ++i) p = p * s + c[i];
  }
  double z = p * x;
  const double spi2 = 0.8862269254527580;  // sqrt(pi)/2
  double ax = fabs(x);
#pragma unroll
  for (int nr = 0; nr < 2; ++nr) {
    if (ax > 0.9375) {
      double az = fabs(z);
      double corr = (erfc(az) - (1.0 - ax)) * spi2 * exp(az * az);
      az += corr;
      z = copysign(az, x);
    } else {
      z -= (erf(z) - x) * spi2 * exp(z * z);
    }
  }
  return z;
}

// ------------------------------- kernels -----------------------------------
__global__ void zero_kernel(double* p, size_t n) {
  size_t i = (size_t)blockIdx.x * blockDim.x + threadIdx.x;
  size_t stride = (size_t)gridDim.x * blockDim.x;
  for (; i < n; i += stride) p[i] = 0.0;
}

__global__ void prng_kernel(double* minv) {
  int tid = blockIdx.x * blockDim.x + threadIdx.x;
  if (tid >= KITER * BATCH * NDIM) return;
  int it = tid / (BATCH * NDIM);
  int i = tid % (BATCH * NDIM);
  unsigned nk0 = 0u, nk1 = (unsigned)it;
  tf_block(0u, 42u, nk0, nk1);                       // fold_in
  unsigned c0 = 0u, c1 = (unsigned)i;                // partitionable counter
  tf_block(nk0, nk1, c0, c1);
  unsigned long long bits = ((unsigned long long)c0 << 32) | (unsigned long long)c1;
  unsigned long long fb = (bits >> 12) | 0x3FF0000000000000ull;
  double f = __builtin_bit_cast(double, fb) - 1.0;
  const double lo = __builtin_bit_cast(double, 0xBFEFFFFFFFFFFFFFull);
  double uu = f * 2.0 + lo;
  if (uu < lo) uu = lo;
  minv[tid] = 1.4142135623730951 * erfinv_d(uu);
}

__global__ void compute_u_kernel(const double2* Theta, const double2* Lamda,
                                 const float* rho, const float* tau, int it,
                                 double2* u) {
  int tid = blockIdx.x * blockDim.x + threadIdx.x;
  if (tid >= BATCH * MDIM) return;
  int b = tid / MDIM, kk = tid % MDIM;
  double r = (double)rho[it], t = (double)tau[it];
  const double2* Lb = Lamda + (size_t)b * NSQ;
  const double2* Tb = Theta + (size_t)b * NSQ;
  double ar = 0.0, ai = 0.0;
  for (int i = 0; i + kk < MDIM; ++i) {
    double2 L = Lb[i * NDIM + i + kk];
    double2 Th = Tb[i * NDIM + i + kk];
    ar += L.x + r * Th.x;
    ai += L.y + r * Th.y;
  }
  if (kk == 0) ar += -(t * 0.5) * (double)MDIM;
  double s = 1.0 / ((double)(MDIM - kk) * r);
  u[b * MDIM + kk] = make_double2(ar * s, ai * s);
}

// A32 = fp32(StackM - Lamda/r) ; U32 = I (identity == its own transpose)
__global__ void assemble_kernel(const double2* Theta, const double2* Lamda,
                                const double2* u, const float* Yre, const float* Yim,
                                const float* rho, const float* tau, int it,
                                float2* A32, float2* U32) {
  int tid = blockIdx.x * 256 + threadIdx.x;
  if (tid >= BATCH * NSQ) return;
  int b = tid / NSQ, rem = tid % NSQ, i = rem / NDIM, j = rem % NDIM;
  double r = (double)rho[it], t = (double)tau[it];
  size_t idx = (size_t)b * NSQ + rem;
  double2 L = Lamda[idx], Th = Theta[idx];
  double axr, axi;
  if (i < MDIM && j < MDIM) {
    int d = j - i;
    double2 uv = u[b * MDIM + (d >= 0 ? d : -d)];
    double uy = (d >= 0) ? uv.y : -uv.y;
    axr = uv.x - L.x / r;
    axi = uy - L.y / r;
  } else if (i < MDIM) {
    double yr = (double)Yre[(b * MDIM + i) * LDIM + (j - MDIM)];
    double yi = (double)Yim[(b * MDIM + i) * LDIM + (j - MDIM)];
    double inv = 1.0 / (1.0 + 2.0 * r);
    axr = (yr + 2.0 * L.x + 2.0 * r * Th.x) * inv - L.x / r;
    axi = (yi + 2.0 * L.y + 2.0 * r * Th.y) * inv - L.y / r;
  } else if (j < MDIM) {
    double yr = (double)Yre[(b * MDIM + j) * LDIM + (i - MDIM)];
    double yi = -(double)Yim[(b * MDIM + j) * LDIM + (i - MDIM)];
    double inv = 1.0 / (1.0 + 2.0 * r);
    axr = (yr + 2.0 * L.x + 2.0 * r * Th.x) * inv - L.x / r;
    axi = (yi + 2.0 * L.y + 2.0 * r * Th.y) * inv - L.y / r;
  } else {
    axr = Th.x - ((i == j) ? t / (2.0 * r) : 0.0);
    axi = Th.y;
  }
  A32[idx] = make_float2((float)axr, (float)axi);
  U32[idx] = make_float2((i == j) ? 1.0f : 0.0f, 0.0f);
}

__device__ __forceinline__ int pair_p(int j, int r) {
  return (j == 0) ? 0 : 1 + (j - 1 + r) % 127;
}
__device__ __forceinline__ int pair_q(int j, int r) {
  return 1 + (126 - j + r) % 127;
}

// fp32 Hermitian parallel-order Jacobi. A in LDS (SoA re/im, stride 129),
// eigenvectors TRANSPOSED (U = V^T) in global -> coalesced row rotations
// merged into pass 1. Fused rank/d1/d2 epilogue. 1024 thr/block, 1 blk/matrix.
__global__ __launch_bounds__(1024) void jacobi32_kernel(
    const float2* __restrict__ A, float2* __restrict__ U,
    const double* __restrict__ minv, int it,
    double* __restrict__ d1, double* __restrict__ d2) {
  extern __shared__ float smem[];
  float* sAre = smem;             // 128 x 129
  float* sAim = smem + NDIM * RS; // 128 x 129
  __shared__ float sc[64], sbr[64], sbi[64];
  __shared__ int sp[64], sq[64];
  __shared__ float s_off[16], s_tot[16];
  __shared__ int s_done;
  int b = blockIdx.x, tid = threadIdx.x;
  const float2* Ag = A + (size_t)b * NSQ;
  float2* Ug = U + (size_t)b * NSQ;
  for (int i = tid; i < NSQ; i += 1024) {
    float2 a = Ag[i];
    int row = i >> 7, col = i & 127;
    sAre[row * RS + col] = a.x;
    sAim[row * RS + col] = a.y;
  }
  __syncthreads();
  for (int sweep = 0; sweep < MAXS; ++sweep) {
    for (int r0 = 0; r0 < 127; ++r0) {
      int r = (sweep & 1) ? (126 - r0) : r0;
      if (tid < 64) {
        int p = pair_p(tid, r), q = pair_q(tid, r);
        sp[tid] = p; sq[tid] = q;
        float app = sAre[p * RS + p], aqq = sAre[q * RS + q];
        float gr = sAre[p * RS + q], gi = sAim[p * RS + q];
        float ag2 = gr * gr + gi * gi;
        float cc = 1.0f, br = 0.0f, bi = 0.0f;
        if (ag2 > 1e-24f) {
          float ag = sqrtf(ag2);
          float ta = (aqq - app) / (2.0f * ag);
          float tt = -copysignf(1.0f, ta) / (fabsf(ta) + sqrtf(1.0f + ta * ta));
          cc = 1.0f / sqrtf(1.0f + tt * tt);
          float tcag = tt * cc / ag;
          br = gr * tcag; bi = gi * tcag;
        }
        sc[tid] = cc; sbr[tid] = br; sbi[tid] = bi;
      }
      __syncthreads();
      // phase A: A row rotations (LDS) + U row rotations (global, coalesced)
      {
        int col = tid & 127, jbase = tid >> 7;
#pragma unroll
        for (int k = 0; k < 8; ++k) {
          int j = jbase + k * 8;
          int p = sp[j], q = sq[j];
          float cc = sc[j], br = sbr[j], bi = sbi[j];
          int ip = p * RS + col, iq = q * RS + col;
          float apr = sAre[ip], api = sAim[ip];
          float aqr = sAre[iq], aqi = sAim[iq];
          sAre[ip] = cc * apr + (br * aqr - bi * aqi);   // c*ap + sb*aq
          sAim[ip] = cc * api + (br * aqi + bi * aqr);
          sAre[iq] = cc * aqr - (br * apr + bi * api);   // c*aq - conj(sb)*ap
          sAim[iq] = cc * aqi - (br * api - bi * apr);
          float2 up = Ug[p * NDIM + col], uq = Ug[q * NDIM + col];
          float2 nup, nuq;                                // U_p <- c U_p + conj(sb) U_q
          nup.x = cc * up.x + (br * uq.x + bi * uq.y);
          nup.y = cc * up.y + (br * uq.y - bi * uq.x);
          nuq.x = cc * uq.x - (br * up.x - bi * up.y);    // U_q <- c U_q - sb U_p
          nuq.y = cc * uq.y - (br * up.y + bi * up.x);
          Ug[p * NDIM + col] = nup; Ug[q * NDIM + col] = nuq;
        }
      }
      __syncthreads();
      // phase B: A column rotations (LDS; distinct p -> ~2 lanes/bank, free)
      {
        int j = tid & 63;
        int p = sp[j], q = sq[j], rowb = tid >> 6;
        float cc = sc[j], br = sbr[j], bi = sbi[j];
#pragma unroll
        for (int k = 0; k < 8; ++k) {
          int row = rowb + k * 16;
          int ip = row * RS + p, iq = row * RS + q;
          float xr = sAre[ip], xi = sAim[ip];
          float yr = sAre[iq], yi = sAim[iq];
          sAre[ip] = cc * xr + (br * yr + bi * yi);   // c*x + conj(sb)*y
          sAim[ip] = cc * xi + (br * yi - bi * yr);
          sAre[iq] = cc * yr - (br * xr - bi * xi);   // c*y - sb*x
          sAim[iq] = cc * yi - (br * xi + bi * xr);
        }
      }
      __syncthreads();
    }
    if (sweep >= 4) {   // convergence: off^2 <= 1e-10 * tot^2
      float off = 0.0f, tot = 0.0f;
      for (int i = tid; i < NSQ; i += 1024) {
        int rr = i >> 7, cl = i & 127;
        float re = sAre[rr * RS + cl], im = sAim[rr * RS + cl];
        float m2 = re * re + im * im;
        tot += m2;
        if (rr != cl) off += m2;
      }
      for (int s = 32; s > 0; s >>= 1) {
        off += __shfl_down(off, s);
        tot += __shfl_down(tot, s);
      }
      if ((tid & 63) == 0) { s_off[tid >> 6] = off; s_tot[tid >> 6] = tot; }
      __syncthreads();
      if (tid == 0) {
        float o = 0.0f, t2 = 0.0f;
        for (int z = 0; z < 16; ++z) { o += s_off[z]; t2 += s_tot[z]; }
        s_done = (o <= 1e-10f * t2) ? 1 : 0;
      }
      __syncthreads();
      if (s_done) break;
    }
  }
  // fused rankd: d1 = relu(w + minv[rank]), d2 = d1 - w
  __syncthreads();
  if (tid < NDIM) {
    float wj = sAre[tid * RS + tid];
    int rank = 0;
    for (int k2 = 0; k2 < NDIM; ++k2) {
      float wk = sAre[k2 * RS + k2];
      rank += (wk < wj) || (wk == wj && k2 < tid);
    }
    double mv = minv[(it * BATCH + b) * NDIM + rank];
    double v = (double)wj + mv;
    if (v < 0.0) v = 0.0;
    d1[b * NDIM + tid] = v;
    d2[b * NDIM + tid] = v - (double)wj;
  }
}

// Theta = V diag(d1) V^H ; Lamda = (1-e/r) Lamda + e * V diag(d2) V^H.
// U = V^T in global; tiles loaded transposed+coalesced into SoA LDS.
__global__ __launch_bounds__(256) void update_kernel(
    const float2* U, const double* d1, const double* d2,
    const float* rho, const float* eta, int it,
    double2* Theta, double2* Lamda) {
  __shared__ float ViRe[32][33], ViIm[32][33];
  __shared__ float VkRe[32][33], VkIm[32][33];
  __shared__ double s1[32], s2[32];
  int blk = blockIdx.x;
  int b = blk >> 4, tile = blk & 15, ti = tile >> 2, tk = tile & 3;
  int tid = threadIdx.x;
  int lk = tid & 31, lig = tid >> 5;
  double r = (double)rho[it], e = (double)eta[it];
  double a1x[4] = {0, 0, 0, 0}, a1y[4] = {0, 0, 0, 0};
  double a2x[4] = {0, 0, 0, 0}, a2y[4] = {0, 0, 0, 0};
  const float2* Ub = U + (size_t)b * NSQ;
  for (int jc = 0; jc < 4; ++jc) {
    for (int e2 = tid; e2 < 1024; e2 += 256) {
      int rr = e2 & 31, cc2 = e2 >> 5;   // rr fastest -> coalesced U rows
      float2 v1 = Ub[(jc * 32 + cc2) * NDIM + ti * 32 + rr];
      ViRe[rr][cc2] = v1.x; ViIm[rr][cc2] = v1.y;
      float2 v2 = Ub[(jc * 32 + cc2) * NDIM + tk * 32 + rr];
      VkRe[rr][cc2] = v2.x; VkIm[rr][cc2] = v2.y;
    }
    if (tid < 32) {
      s1[tid] = d1[b * NDIM + jc * 32 + tid];
      s2[tid] = d2[b * NDIM + jc * 32 + tid];
    }
    __syncthreads();
#pragma unroll
    for (int uo = 0; uo < 4; ++uo) {
      int li = lig + uo * 8;
      double ax = a1x[uo], ay = a1y[uo], bx = a2x[uo], by = a2y[uo];
      for (int j = 0; j < 32; ++j) {
        float var = ViRe[li][j], vai = ViIm[li][j];
        float vbr = VkRe[lk][j], vbi = VkIm[lk][j];
        double pr = (double)(var * vbr + vai * vbi);
        double pi = (double)(vai * vbr - var * vbi);
        ax += s1[j] * pr; ay += s1[j] * pi;
        bx += s2[j] * pr; by += s2[j] * pi;
      }
      a1x[uo] = ax; a1y[uo] = ay; a2x[uo] = bx; a2y[uo] = by;
    }
    __syncthreads();
  }
  double lf = 1.0 - e / r;
#pragma unroll
  for (int uo = 0; uo < 4; ++uo) {
    int gi = ti * 32 + lig + uo * 8, gk = tk * 32 + lk;
    size_t idx = (size_t)b * NSQ + gi * NDIM + gk;
    Theta[idx] = make_double2(a1x[uo], a1y[uo]);
    double2 Lold = Lamda[idx];
    Lamda[idx] = make_double2(lf * Lold.x + e * a2x[uo], lf * Lold.y + e * a2y[uo]);
  }
}

// OUTPUT (float32 real parts): T[i][j] = u[|i-j|].re ; uvec.re = u.re
__global__ void writeout_kernel(const double2* u, float* out) {
  int tid = blockIdx.x * 256 + threadIdx.x;
  if (tid >= OUT_ELEMS) return;
  double re;
  if (tid < BATCH * MDIM * MDIM) {
    int b = tid >> 12, rem = tid & 4095, i = rem >> 6, j = rem & 63;
    int d = j - i;
    re = u[b * MDIM + (d >= 0 ? d : -d)].x;
  } else {
    int k2 = tid - BATCH * MDIM * MDIM;
    int b = k2 >> 6, kk = k2 & 63;
    re = u[b * MDIM + kk].x;
  }
  out[tid] = (float)re;
}

// ------------------------------- launch ------------------------------------
extern "C" void kernel_launch(void* const* d_in, const int* in_sizes, int n_in,
                              void* d_out, int out_size, void* d_ws, size_t ws_size,
                              hipStream_t stream) {
  const float* Yre = (const float*)d_in[0];
  const float* Yim = (const float*)d_in[1];
  const float* rho = (const float*)d_in[2];
  const float* tau = (const float*)d_in[3];
  const float* eta = (const float*)d_in[4];
  float* out = (float*)d_out;

  char* ws = (char*)d_ws;
  size_t off = 0;
  auto take = [&](size_t bytes) -> char* {
    char* p = ws + off;
    off += (bytes + 255) & ~(size_t)255;
    return p;
  };
  double2* u     = (double2*)take((size_t)BATCH * MDIM * sizeof(double2));
  double*  minv  = (double*)take((size_t)KITER * BATCH * NDIM * sizeof(double));
  double*  d1    = (double*)take((size_t)BATCH * NDIM * sizeof(double));
  double*  d2    = (double*)take((size_t)BATCH * NDIM * sizeof(double));
  double2* Lamda = (double2*)take((size_t)BATCH * NSQ * sizeof(double2));  // 16.8 MB
  double2* Theta = (double2*)take((size_t)BATCH * NSQ * sizeof(double2));  // 16.8 MB
  float2*  A32   = (float2*)take((size_t)BATCH * NSQ * sizeof(float2));    //  8.4 MB
  float2*  U32   = (float2*)take((size_t)BATCH * NSQ * sizeof(float2));    //  8.4 MB
  (void)in_sizes; (void)n_in; (void)ws_size; (void)out_size;  // ~51 MB total

  hipFuncSetAttribute((const void*)jacobi32_kernel,
                      hipFuncAttributeMaxDynamicSharedMemorySize, JAC_LDS_BYTES);

  zero_kernel<<<2048, 256, 0, stream>>>((double*)Theta, (size_t)BATCH * NSQ * 2);
  zero_kernel<<<2048, 256, 0, stream>>>((double*)Lamda, (size_t)BATCH * NSQ * 2);
  prng_kernel<<<(KITER * BATCH * NDIM + 255) / 256, 256, 0, stream>>>(minv);

  for (int it = 0; it < KITER - 1; ++it) {
    compute_u_kernel<<<16, 256, 0, stream>>>(Theta, Lamda, rho, tau, it, u);
    assemble_kernel<<<BATCH * NSQ / 256, 256, 0, stream>>>(Theta, Lamda, u, Yre, Yim,
                                                           rho, tau, it, A32, U32);
    jacobi32_kernel<<<BATCH, 1024, JAC_LDS_BYTES, stream>>>(A32, U32, minv, it, d1, d2);
    update_kernel<<<BATCH * 16, 256, 0, stream>>>(U32, d1, d2, rho, eta, it, Theta, Lamda);
  }
  compute_u_kernel<<<16, 256, 0, stream>>>(Theta, Lamda, rho, tau, KITER - 1, u);
  writeout_kernel<<<(OUT_ELEMS + 255) / 256, 256, 0, stream>>>(u, out);
}

// Round 8
// 38861.606 us; speedup vs baseline: 11.0833x; 2.0865x over previous
//
#include <hip/hip_runtime.h>
#include <stdint.h>

// ---------------------------------------------------------------------------
// AnmNetwork: ADMM-like complex PSD iteration. B=64, m=l=64, n=128, K=10.
//  * Sita = V relu(w + minv[rank]) V^H  (second eigh mathematically redundant)
//  * Lamda_new = (1 - eta/rho) Lamda + eta * V diag(relu(w+m)-w) V^H
//  * Output depends only on state entering iteration K-1 -> 9 eigh rounds.
//  * PRNG: JAX threefry2x32 partitionable counters (bit-exact, R5).
// R8 (jacobi is latency/critical-path bound: VALUBusy 10%, R7 conflict fix
// was neutral; adaptive exit likely never fired -> 16 sweeps):
//  * FIXED 6 sweeps, convergence check removed (fp32 plateau by sweep ~6).
//  * Fused one-pass rotation: thread transforms 2x2 pair-block B <- L_i B R_j
//    -> ONE LDS pass + 2 barriers/round (was two passes + 3 barriers).
//  * U = V^T rows rotated in the same phase (coalesced, L2-resident).
// State (Theta/Lamda), PRNG, u, writeout stay fp64.
// ---------------------------------------------------------------------------

#define BATCH 64
#define MDIM 64
#define LDIM 64
#define NDIM 128
#define NSQ (NDIM * NDIM)
#define KITER 10
#define SWEEPS 6
#define RS 129                                  // LDS row stride (floats)
#define JAC_LDS_BYTES (2 * NDIM * RS * (int)sizeof(float))   // 132,096 B
#define OUT_ELEMS 266240   // 64*64*64 (T) + 64*64 (uvec), f32 real parts

// ----------------------------- threefry2x32 --------------------------------
__device__ __forceinline__ void tf_block(unsigned k0, unsigned k1,
                                         unsigned& x0, unsigned& x1) {
  unsigned k2 = k0 ^ k1 ^ 0x1BD11BDAu;
  x0 += k0; x1 += k1;
#define TF_R(r) { x0 += x1; x1 = (x1 << (r)) | (x1 >> (32 - (r))); x1 ^= x0; }
  TF_R(13) TF_R(15) TF_R(26) TF_R(6)
  x0 += k1; x1 += k2 + 1u;
  TF_R(17) TF_R(29) TF_R(16) TF_R(24)
  x0 += k2; x1 += k0 + 2u;
  TF_R(13) TF_R(15) TF_R(26) TF_R(6)
  x0 += k0; x1 += k1 + 3u;
  TF_R(17) TF_R(29) TF_R(16) TF_R(24)
  x0 += k1; x1 += k2 + 4u;
  TF_R(13) TF_R(15) TF_R(26) TF_R(6)
  x0 += k2; x1 += k0 + 5u;
#undef TF_R
}

// ------------------------------- erfinv (f64) ------------------------------
__device__ double erfinv_d(double x) {
  double w = -log1p(-x * x);
  double p;
  if (w < 6.25) {
    w -= 3.125;
    const double c[23] = {
      -3.6444120640178196996e-21, -1.685059138182016589e-19,
      1.2858480715256400167e-18,  1.115787767802518096e-17,
      -1.333171662854620906e-16,  2.0972767875968561637e-17,
      6.6376381343583238325e-15,  -4.0545662729752068639e-14,
      -8.1519341976054721522e-14, 2.6335093153082322977e-12,
      -1.2975133253453532498e-11, -5.4154120542946279317e-11,
      1.051212273321532285e-09,   -4.1126339803469836976e-09,
      -2.9070369957882005086e-08, 4.2347877827932403518e-07,
      -1.3654692000834678645e-06, -1.3882523362786468719e-05,
      1.8673420803405714802e-04,  -7.4070253416626697512e-04,
      -6.0336708714301490533e-03, 2.4015818242558961693e-01,
      1.6536545626831027356e+00};
    p = c[0];
#pragma unroll
    for (int i = 1; i < 23; ++i) p = p * w + c[i];
  } else if (w < 16.0) {
    double s = sqrt(w) - 3.25;
    const double c[19] = {
      2.2137376921775787049e-09,  9.0756561938885390979e-08,
      -2.7517406297064545428e-07, 1.8239629214389227755e-08,
      1.5027403968909827627e-06,  -4.013867526981545969e-06,
      2.9234449089955446044e-06,  1.2475304481671778723e-05,
      -4.7318229009055733981e-05, 6.8284851459573175448e-05,
      2.4031110387097893999e-05,  -3.5503752036284748449e-04,
      9.5328937973738049703e-04,  -1.6882755560235047313e-03,
      2.4914420961078508066e-03,  -3.7512085075692412107e-03,
      5.3709145535900636051e-03,  1.0052589676941592334e+00,
      3.0838856104922207635e+00};
    p = c[0];
#pragma unroll
    for (int i = 1; i < 19; ++i) p = p * s + c[i];
  } else {
    double s = sqrt(w) - 5.0;
    const double c[17] = {
      -2.7109920616438573243e-11, -2.5556418169965252055e-10,
      1.5076572693500548083e-09,  -3.7894654401267369937e-09,
      7.6157012080783393804e-09,  -1.4960026627149240478e-08,
      2.9147953450901080826e-08,  -6.7711997758452339498e-08,
      2.2900482228026654717e-07,  -9.9298272942317002539e-07,
      4.5260625972231537039e-06,  -1.9681778105531670567e-05,
      7.5995277030017761139e-05,  -2.1503011930044477347e-04,
      -1.3871931833623122026e-04, 1.0103004648645343977e+00,
      4.8499064014085844221e+00};
    p = c[0];
#pragma unroll
    for (int i = 1; i < 17; ++i) p = p * s + c[i];
  }
  double z = p * x;
  const double spi2 = 0.8862269254527580;  // sqrt(pi)/2
  double ax = fabs(x);
#pragma unroll
  for (int nr = 0; nr < 2; ++nr) {
    if (ax > 0.9375) {
      double az = fabs(z);
      double corr = (erfc(az) - (1.0 - ax)) * spi2 * exp(az * az);
      az += corr;
      z = copysign(az, x);
    } else {
      z -= (erf(z) - x) * spi2 * exp(z * z);
    }
  }
  return z;
}

// ------------------------------- kernels -----------------------------------
__global__ void zero_kernel(double* p, size_t n) {
  size_t i = (size_t)blockIdx.x * blockDim.x + threadIdx.x;
  size_t stride = (size_t)gridDim.x * blockDim.x;
  for (; i < n; i += stride) p[i] = 0.0;
}

__global__ void prng_kernel(double* minv) {
  int tid = blockIdx.x * blockDim.x + threadIdx.x;
  if (tid >= KITER * BATCH * NDIM) return;
  int it = tid / (BATCH * NDIM);
  int i = tid % (BATCH * NDIM);
  unsigned nk0 = 0u, nk1 = (unsigned)it;
  tf_block(0u, 42u, nk0, nk1);                       // fold_in
  unsigned c0 = 0u, c1 = (unsigned)i;                // partitionable counter
  tf_block(nk0, nk1, c0, c1);
  unsigned long long bits = ((unsigned long long)c0 << 32) | (unsigned long long)c1;
  unsigned long long fb = (bits >> 12) | 0x3FF0000000000000ull;
  double f = __builtin_bit_cast(double, fb) - 1.0;
  const double lo = __builtin_bit_cast(double, 0xBFEFFFFFFFFFFFFFull);
  double uu = f * 2.0 + lo;
  if (uu < lo) uu = lo;
  minv[tid] = 1.4142135623730951 * erfinv_d(uu);
}

__global__ void compute_u_kernel(const double2* Theta, const double2* Lamda,
                                 const float* rho, const float* tau, int it,
                                 double2* u) {
  int tid = blockIdx.x * blockDim.x + threadIdx.x;
  if (tid >= BATCH * MDIM) return;
  int b = tid / MDIM, kk = tid % MDIM;
  double r = (double)rho[it], t = (double)tau[it];
  const double2* Lb = Lamda + (size_t)b * NSQ;
  const double2* Tb = Theta + (size_t)b * NSQ;
  double ar = 0.0, ai = 0.0;
  for (int i = 0; i + kk < MDIM; ++i) {
    double2 L = Lb[i * NDIM + i + kk];
    double2 Th = Tb[i * NDIM + i + kk];
    ar += L.x + r * Th.x;
    ai += L.y + r * Th.y;
  }
  if (kk == 0) ar += -(t * 0.5) * (double)MDIM;
  double s = 1.0 / ((double)(MDIM - kk) * r);
  u[b * MDIM + kk] = make_double2(ar * s, ai * s);
}

// A32 = fp32(StackM - Lamda/r) ; U32 = I (identity == its own transpose)
__global__ void assemble_kernel(const double2* Theta, const double2* Lamda,
                                const double2* u, const float* Yre, const float* Yim,
                                const float* rho, const float* tau, int it,
                                float2* A32, float2* U32) {
  int tid = blockIdx.x * 256 + threadIdx.x;
  if (tid >= BATCH * NSQ) return;
  int b = tid / NSQ, rem = tid % NSQ, i = rem / NDIM, j = rem % NDIM;
  double r = (double)rho[it], t = (double)tau[it];
  size_t idx = (size_t)b * NSQ + rem;
  double2 L = Lamda[idx], Th = Theta[idx];
  double axr, axi;
  if (i < MDIM && j < MDIM) {
    int d = j - i;
    double2 uv = u[b * MDIM + (d >= 0 ? d : -d)];
    double uy = (d >= 0) ? uv.y : -uv.y;
    axr = uv.x - L.x / r;
    axi = uy - L.y / r;
  } else if (i < MDIM) {
    double yr = (double)Yre[(b * MDIM + i) * LDIM + (j - MDIM)];
    double yi = (double)Yim[(b * MDIM + i) * LDIM + (j - MDIM)];
    double inv = 1.0 / (1.0 + 2.0 * r);
    axr = (yr + 2.0 * L.x + 2.0 * r * Th.x) * inv - L.x / r;
    axi = (yi + 2.0 * L.y + 2.0 * r * Th.y) * inv - L.y / r;
  } else if (j < MDIM) {
    double yr = (double)Yre[(b * MDIM + j) * LDIM + (i - MDIM)];
    double yi = -(double)Yim[(b * MDIM + j) * LDIM + (i - MDIM)];
    double inv = 1.0 / (1.0 + 2.0 * r);
    axr = (yr + 2.0 * L.x + 2.0 * r * Th.x) * inv - L.x / r;
    axi = (yi + 2.0 * L.y + 2.0 * r * Th.y) * inv - L.y / r;
  } else {
    axr = Th.x - ((i == j) ? t / (2.0 * r) : 0.0);
    axi = Th.y;
  }
  A32[idx] = make_float2((float)axr, (float)axi);
  U32[idx] = make_float2((i == j) ? 1.0f : 0.0f, 0.0f);
}

__device__ __forceinline__ int pair_p(int j, int r) {
  return (j == 0) ? 0 : 1 + (j - 1 + r) % 127;
}
__device__ __forceinline__ int pair_q(int j, int r) {
  return 1 + (126 - j + r) % 127;
}

// fp32 Hermitian parallel-order Jacobi, fused one-pass 2x2 block rotations.
// A in LDS (SoA re/im, stride 129); U = V^T rows in global (L2-resident).
// Fixed SWEEPS sweeps; 2 barriers/round. Fused rank/d1/d2 epilogue.
__global__ __launch_bounds__(1024) void jacobi32_kernel(
    const float2* __restrict__ A, float2* __restrict__ U,
    const double* __restrict__ minv, int it,
    double* __restrict__ d1, double* __restrict__ d2) {
  extern __shared__ float smem[];
  float* sAre = smem;             // 128 x 129
  float* sAim = smem + NDIM * RS; // 128 x 129
  __shared__ float sc[64], sbr[64], sbi[64];
  __shared__ int sp[64], sq[64];
  int b = blockIdx.x, tid = threadIdx.x;
  const float2* Ag = A + (size_t)b * NSQ;
  float2* Ug = U + (size_t)b * NSQ;
  for (int i = tid; i < NSQ; i += 1024) {
    float2 a = Ag[i];
    sAre[(i >> 7) * RS + (i & 127)] = a.x;
    sAim[(i >> 7) * RS + (i & 127)] = a.y;
  }
  __syncthreads();
  for (int sweep = 0; sweep < SWEEPS; ++sweep) {
    for (int r0 = 0; r0 < 127; ++r0) {
      int r = (sweep & 1) ? (126 - r0) : r0;
      if (tid < 64) {
        int p = pair_p(tid, r), q = pair_q(tid, r);
        sp[tid] = p; sq[tid] = q;
        float app = sAre[p * RS + p], aqq = sAre[q * RS + q];
        float gr = sAre[p * RS + q], gi = sAim[p * RS + q];
        float ag2 = gr * gr + gi * gi;
        float cc = 1.0f, br = 0.0f, bi = 0.0f;
        if (ag2 > 1e-24f) {
          float ag = sqrtf(ag2);
          float ta = (aqq - app) / (2.0f * ag);
          float tt = -copysignf(1.0f, ta) / (fabsf(ta) + sqrtf(1.0f + ta * ta));
          cc = 1.0f / sqrtf(1.0f + tt * tt);
          float tcag = tt * cc / ag;
          br = gr * tcag; bi = gi * tcag;
        }
        sc[tid] = cc; sbr[tid] = br; sbi[tid] = bi;
      }
      __syncthreads();
      // Fused pass: A pair-block (i,j): B <- L_i * B * R_j  (one LDS touch)
      //   L_i: row_p' = c*row_p + sb*row_q ; row_q' = c*row_q - conj(sb)*row_p
      //   R_j: col_p' = c*col_p + conj(sb)*col_q ; col_q' = c*col_q - sb*col_p
      {
        int j = tid & 63, i0 = tid >> 6;       // lane j distinct in wave
        int pj = sp[j], qj = sq[j];
        float cj = sc[j], brj = sbr[j], bij = sbi[j];
#pragma unroll
        for (int k = 0; k < 4; ++k) {
          int i = i0 + 16 * k;
          int pi = sp[i], qi = sq[i];
          float ci = sc[i], bri = sbr[i], bii = sbi[i];
          int i00 = pi * RS + pj, i01 = pi * RS + qj;
          int i10 = qi * RS + pj, i11 = qi * RS + qj;
          float b00r = sAre[i00], b00i = sAim[i00];
          float b01r = sAre[i01], b01i = sAim[i01];
          float b10r = sAre[i10], b10i = sAim[i10];
          float b11r = sAre[i11], b11i = sAim[i11];
          // left: T = L_i * B   (sb_i = (bri,bii))
          float t00r = ci * b00r + (bri * b10r - bii * b10i);
          float t00i = ci * b00i + (bri * b10i + bii * b10r);
          float t01r = ci * b01r + (bri * b11r - bii * b11i);
          float t01i = ci * b01i + (bri * b11i + bii * b11r);
          float t10r = ci * b10r - (bri * b00r + bii * b00i);
          float t10i = ci * b10i - (bri * b00i - bii * b00r);
          float t11r = ci * b11r - (bri * b01r + bii * b01i);
          float t11i = ci * b11i - (bri * b01i - bii * b01r);
          // right: C = T * R_j  (col_p' = c*colp + conj(sb_j)*colq; col_q' = c*colq - sb_j*colp)
          sAre[i00] = cj * t00r + (brj * t01r + bij * t01i);
          sAim[i00] = cj * t00i + (brj * t01i - bij * t01r);
          sAre[i01] = cj * t01r - (brj * t00r - bij * t00i);
          sAim[i01] = cj * t01i - (brj * t00i + bij * t00r);
          sAre[i10] = cj * t10r + (brj * t11r + bij * t11i);
          sAim[i10] = cj * t10i + (brj * t11i - bij * t11r);
          sAre[i11] = cj * t11r - (brj * t10r - bij * t10i);
          sAim[i11] = cj * t11i - (brj * t10i + bij * t10r);
        }
      }
      // U row rotations (global, coalesced), same barrier region
      {
        int col = tid & 127, jbase = tid >> 7;
#pragma unroll
        for (int k = 0; k < 8; ++k) {
          int j = jbase + k * 8;
          int p = sp[j], q = sq[j];
          float cc = sc[j], br = sbr[j], bi = sbi[j];
          float2 up = Ug[p * NDIM + col], uq = Ug[q * NDIM + col];
          float2 nup, nuq;                             // U_p <- c U_p + conj(sb) U_q
          nup.x = cc * up.x + (br * uq.x + bi * uq.y);
          nup.y = cc * up.y + (br * uq.y - bi * uq.x);
          nuq.x = cc * uq.x - (br * up.x - bi * up.y); // U_q <- c U_q - sb U_p
          nuq.y = cc * uq.y - (br * up.y + bi * up.x);
          Ug[p * NDIM + col] = nup; Ug[q * NDIM + col] = nuq;
        }
      }
      __syncthreads();
    }
  }
  // fused rankd: d1 = relu(w + minv[rank]), d2 = d1 - w
  if (tid < NDIM) {
    float wj = sAre[tid * RS + tid];
    int rank = 0;
    for (int k2 = 0; k2 < NDIM; ++k2) {
      float wk = sAre[k2 * RS + k2];
      rank += (wk < wj) || (wk == wj && k2 < tid);
    }
    double mv = minv[(it * BATCH + b) * NDIM + rank];
    double v = (double)wj + mv;
    if (v < 0.0) v = 0.0;
    d1[b * NDIM + tid] = v;
    d2[b * NDIM + tid] = v - (double)wj;
  }
}

// Theta = V diag(d1) V^H ; Lamda = (1-e/r) Lamda + e * V diag(d2) V^H.
// U = V^T in global; tiles loaded transposed+coalesced into SoA LDS.
__global__ __launch_bounds__(256) void update_kernel(
    const float2* U, const double* d1, const double* d2,
    const float* rho, const float* eta, int it,
    double2* Theta, double2* Lamda) {
  __shared__ float ViRe[32][33], ViIm[32][33];
  __shared__ float VkRe[32][33], VkIm[32][33];
  __shared__ double s1[32], s2[32];
  int blk = blockIdx.x;
  int b = blk >> 4, tile = blk & 15, ti = tile >> 2, tk = tile & 3;
  int tid = threadIdx.x;
  int lk = tid & 31, lig = tid >> 5;
  double r = (double)rho[it], e = (double)eta[it];
  double a1x[4] = {0, 0, 0, 0}, a1y[4] = {0, 0, 0, 0};
  double a2x[4] = {0, 0, 0, 0}, a2y[4] = {0, 0, 0, 0};
  const float2* Ub = U + (size_t)b * NSQ;
  for (int jc = 0; jc < 4; ++jc) {
    for (int e2 = tid; e2 < 1024; e2 += 256) {
      int rr = e2 & 31, cc2 = e2 >> 5;   // rr fastest -> coalesced U rows
      float2 v1 = Ub[(jc * 32 + cc2) * NDIM + ti * 32 + rr];
      ViRe[rr][cc2] = v1.x; ViIm[rr][cc2] = v1.y;
      float2 v2 = Ub[(jc * 32 + cc2) * NDIM + tk * 32 + rr];
      VkRe[rr][cc2] = v2.x; VkIm[rr][cc2] = v2.y;
    }
    if (tid < 32) {
      s1[tid] = d1[b * NDIM + jc * 32 + tid];
      s2[tid] = d2[b * NDIM + jc * 32 + tid];
    }
    __syncthreads();
#pragma unroll
    for (int uo = 0; uo < 4; ++uo) {
      int li = lig + uo * 8;
      double ax = a1x[uo], ay = a1y[uo], bx = a2x[uo], by = a2y[uo];
      for (int j = 0; j < 32; ++j) {
        float var = ViRe[li][j], vai = ViIm[li][j];
        float vbr = VkRe[lk][j], vbi = VkIm[lk][j];
        double pr = (double)(var * vbr + vai * vbi);
        double pi = (double)(vai * vbr - var * vbi);
        ax += s1[j] * pr; ay += s1[j] * pi;
        bx += s2[j] * pr; by += s2[j] * pi;
      }
      a1x[uo] = ax; a1y[uo] = ay; a2x[uo] = bx; a2y[uo] = by;
    }
    __syncthreads();
  }
  double lf = 1.0 - e / r;
#pragma unroll
  for (int uo = 0; uo < 4; ++uo) {
    int gi = ti * 32 + lig + uo * 8, gk = tk * 32 + lk;
    size_t idx = (size_t)b * NSQ + gi * NDIM + gk;
    Theta[idx] = make_double2(a1x[uo], a1y[uo]);
    double2 Lold = Lamda[idx];
    Lamda[idx] = make_double2(lf * Lold.x + e * a2x[uo], lf * Lold.y + e * a2y[uo]);
  }
}

// OUTPUT (float32 real parts): T[i][j] = u[|i-j|].re ; uvec.re = u.re
__global__ void writeout_kernel(const double2* u, float* out) {
  int tid = blockIdx.x * 256 + threadIdx.x;
  if (tid >= OUT_ELEMS) return;
  double re;
  if (tid < BATCH * MDIM * MDIM) {
    int b = tid >> 12, rem = tid & 4095, i = rem >> 6, j = rem & 63;
    int d = j - i;
    re = u[b * MDIM + (d >= 0 ? d : -d)].x;
  } else {
    int k2 = tid - BATCH * MDIM * MDIM;
    int b = k2 >> 6, kk = k2 & 63;
    re = u[b * MDIM + kk].x;
  }
  out[tid] = (float)re;
}

// ------------------------------- launch ------------------------------------
extern "C" void kernel_launch(void* const* d_in, const int* in_sizes, int n_in,
                              void* d_out, int out_size, void* d_ws, size_t ws_size,
                              hipStream_t stream) {
  const float* Yre = (const float*)d_in[0];
  const float* Yim = (const float*)d_in[1];
  const float* rho = (const float*)d_in[2];
  const float* tau = (const float*)d_in[3];
  const float* eta = (const float*)d_in[4];
  float* out = (float*)d_out;

  char* ws = (char*)d_ws;
  size_t off = 0;
  auto take = [&](size_t bytes) -> char* {
    char* p = ws + off;
    off += (bytes + 255) & ~(size_t)255;
    return p;
  };
  double2* u     = (double2*)take((size_t)BATCH * MDIM * sizeof(double2));
  double*  minv  = (double*)take((size_t)KITER * BATCH * NDIM * sizeof(double));
  double*  d1    = (double*)take((size_t)BATCH * NDIM * sizeof(double));
  double*  d2    = (double*)take((size_t)BATCH * NDIM * sizeof(double));
  double2* Lamda = (double2*)take((size_t)BATCH * NSQ * sizeof(double2));  // 16.8 MB
  double2* Theta = (double2*)take((size_t)BATCH * NSQ * sizeof(double2));  // 16.8 MB
  float2*  A32   = (float2*)take((size_t)BATCH * NSQ * sizeof(float2));    //  8.4 MB
  float2*  U32   = (float2*)take((size_t)BATCH * NSQ * sizeof(float2));    //  8.4 MB
  (void)in_sizes; (void)n_in; (void)ws_size; (void)out_size;  // ~51 MB total

  hipFuncSetAttribute((const void*)jacobi32_kernel,
                      hipFuncAttributeMaxDynamicSharedMemorySize, JAC_LDS_BYTES);

  zero_kernel<<<2048, 256, 0, stream>>>((double*)Theta, (size_t)BATCH * NSQ * 2);
  zero_kernel<<<2048, 256, 0, stream>>>((double*)Lamda, (size_t)BATCH * NSQ * 2);
  prng_kernel<<<(KITER * BATCH * NDIM + 255) / 256, 256, 0, stream>>>(minv);

  for (int it = 0; it < KITER - 1; ++it) {
    compute_u_kernel<<<16, 256, 0, stream>>>(Theta, Lamda, rho, tau, it, u);
    assemble_kernel<<<BATCH * NSQ / 256, 256, 0, stream>>>(Theta, Lamda, u, Yre, Yim,
                                                           rho, tau, it, A32, U32);
    jacobi32_kernel<<<BATCH, 1024, JAC_LDS_BYTES, stream>>>(A32, U32, minv, it, d1, d2);
    update_kernel<<<BATCH * 16, 256, 0, stream>>>(U32, d1, d2, rho, eta, it, Theta, Lamda);
  }
  compute_u_kernel<<<16, 256, 0, stream>>>(Theta, Lamda, rho, tau, KITER - 1, u);
  writeout_kernel<<<(OUT_ELEMS + 255) / 256, 256, 0, stream>>>(u, out);
}

// Round 9
// 30708.209 us; speedup vs baseline: 14.0260x; 1.2655x over previous
//
#include <hip/hip_runtime.h>
#include <stdint.h>

// ---------------------------------------------------------------------------
// AnmNetwork: ADMM-like complex PSD iteration. B=64, m=l=64, n=128, K=10.
//  * Sita = V relu(w + minv[rank]) V^H  (second eigh mathematically redundant)
//  * Lamda_new = (1 - eta/rho) Lamda + eta * V diag(relu(w+m)-w) V^H
//  * Output depends only on state entering iteration K-1 -> 9 eigh rounds.
//  * PRNG: JAX threefry2x32 partitionable counters (bit-exact, R5).
// R9 (U rotation through L2 was ~1.8us of the ~5.4us round):
//  * jacobi loop strips U entirely; records (br,bi) per pair per round.
//  * replay_kernel reconstructs U: each WAVE owns a 128x8 column chunk in
//    LDS (SoA stride 9, conflict-free) and replays 127 rounds with ZERO
//    barriers (same-wave LDS ops are in-order; wave_barrier pins sched).
//  * per-sweep jacobi dispatches (A via L2 between sweeps); SWEEPS 6->7 to
//    restore absmax margin (was 0.1855 vs 0.2475); block 512.
// State (Theta/Lamda), PRNG, u, writeout stay fp64.
// ---------------------------------------------------------------------------

#define BATCH 64
#define MDIM 64
#define LDIM 64
#define NDIM 128
#define NSQ (NDIM * NDIM)
#define KITER 10
#define SWEEPS 7
#define RS 129                                  // jacobi LDS row stride (floats)
#define JAC_LDS_BYTES (2 * NDIM * RS * (int)sizeof(float))   // 132,096 B
#define RCH 9                                   // replay chunk col stride
#define REP_LDS_BYTES (8 * 2 * NDIM * RCH * (int)sizeof(float)) // 73,728 B
#define OUT_ELEMS 266240   // 64*64*64 (T) + 64*64 (uvec), f32 real parts

// ----------------------------- threefry2x32 --------------------------------
__device__ __forceinline__ void tf_block(unsigned k0, unsigned k1,
                                         unsigned& x0, unsigned& x1) {
  unsigned k2 = k0 ^ k1 ^ 0x1BD11BDAu;
  x0 += k0; x1 += k1;
#define TF_R(r) { x0 += x1; x1 = (x1 << (r)) | (x1 >> (32 - (r))); x1 ^= x0; }
  TF_R(13) TF_R(15) TF_R(26) TF_R(6)
  x0 += k1; x1 += k2 + 1u;
  TF_R(17) TF_R(29) TF_R(16) TF_R(24)
  x0 += k2; x1 += k0 + 2u;
  TF_R(13) TF_R(15) TF_R(26) TF_R(6)
  x0 += k0; x1 += k1 + 3u;
  TF_R(17) TF_R(29) TF_R(16) TF_R(24)
  x0 += k1; x1 += k2 + 4u;
  TF_R(13) TF_R(15) TF_R(26) TF_R(6)
  x0 += k2; x1 += k0 + 5u;
#undef TF_R
}

// ------------------------------- erfinv (f64) ------------------------------
__device__ double erfinv_d(double x) {
  double w = -log1p(-x * x);
  double p;
  if (w < 6.25) {
    w -= 3.125;
    const double c[23] = {
      -3.6444120640178196996e-21, -1.685059138182016589e-19,
      1.2858480715256400167e-18,  1.115787767802518096e-17,
      -1.333171662854620906e-16,  2.0972767875968561637e-17,
      6.6376381343583238325e-15,  -4.0545662729752068639e-14,
      -8.1519341976054721522e-14, 2.6335093153082322977e-12,
      -1.2975133253453532498e-11, -5.4154120542946279317e-11,
      1.051212273321532285e-09,   -4.1126339803469836976e-09,
      -2.9070369957882005086e-08, 4.2347877827932403518e-07,
      -1.3654692000834678645e-06, -1.3882523362786468719e-05,
      1.8673420803405714802e-04,  -7.4070253416626697512e-04,
      -6.0336708714301490533e-03, 2.4015818242558961693e-01,
      1.6536545626831027356e+00};
    p = c[0];
#pragma unroll
    for (int i = 1; i < 23; ++i) p = p * w + c[i];
  } else if (w < 16.0) {
    double s = sqrt(w) - 3.25;
    const double c[19] = {
      2.2137376921775787049e-09,  9.0756561938885390979e-08,
      -2.7517406297064545428e-07, 1.8239629214389227755e-08,
      1.5027403968909827627e-06,  -4.013867526981545969e-06,
      2.9234449089955446044e-06,  1.2475304481671778723e-05,
      -4.7318229009055733981e-05, 6.8284851459573175448e-05,
      2.4031110387097893999e-05,  -3.5503752036284748449e-04,
      9.5328937973738049703e-04,  -1.6882755560235047313e-03,
      2.4914420961078508066e-03,  -3.7512085075692412107e-03,
      5.3709145535900636051e-03,  1.0052589676941592334e+00,
      3.0838856104922207635e+00};
    p = c[0];
#pragma unroll
    for (int i = 1; i < 19; ++i) p = p * s + c[i];
  } else {
    double s = sqrt(w) - 5.0;
    const double c[17] = {
      -2.7109920616438573243e-11, -2.5556418169965252055e-10,
      1.5076572693500548083e-09,  -3.7894654401267369937e-09,
      7.6157012080783393804e-09,  -1.4960026627149240478e-08,
      2.9147953450901080826e-08,  -6.7711997758452339498e-08,
      2.2900482228026654717e-07,  -9.9298272942317002539e-07,
      4.5260625972231537039e-06,  -1.9681778105531670567e-05,
      7.5995277030017761139e-05,  -2.1503011930044477347e-04,
      -1.3871931833623122026e-04, 1.0103004648645343977e+00,
      4.8499064014085844221e+00};
    p = c[0];
#pragma unroll
    for (int i = 1; i < 17; ++i) p = p * s + c[i];
  }
  double z = p * x;
  const double spi2 = 0.8862269254527580;  // sqrt(pi)/2
  double ax = fabs(x);
#pragma unroll
  for (int nr = 0; nr < 2; ++nr) {
    if (ax > 0.9375) {
      double az = fabs(z);
      double corr = (erfc(az) - (1.0 - ax)) * spi2 * exp(az * az);
      az += corr;
      z = copysign(az, x);
    } else {
      z -= (erf(z) - x) * spi2 * exp(z * z);
    }
  }
  return z;
}

// ------------------------------- kernels -----------------------------------
__global__ void zero_kernel(double* p, size_t n) {
  size_t i = (size_t)blockIdx.x * blockDim.x + threadIdx.x;
  size_t stride = (size_t)gridDim.x * blockDim.x;
  for (; i < n; i += stride) p[i] = 0.0;
}

__global__ void prng_kernel(double* minv) {
  int tid = blockIdx.x * blockDim.x + threadIdx.x;
  if (tid >= KITER * BATCH * NDIM) return;
  int it = tid / (BATCH * NDIM);
  int i = tid % (BATCH * NDIM);
  unsigned nk0 = 0u, nk1 = (unsigned)it;
  tf_block(0u, 42u, nk0, nk1);                       // fold_in
  unsigned c0 = 0u, c1 = (unsigned)i;                // partitionable counter
  tf_block(nk0, nk1, c0, c1);
  unsigned long long bits = ((unsigned long long)c0 << 32) | (unsigned long long)c1;
  unsigned long long fb = (bits >> 12) | 0x3FF0000000000000ull;
  double f = __builtin_bit_cast(double, fb) - 1.0;
  const double lo = __builtin_bit_cast(double, 0xBFEFFFFFFFFFFFFFull);
  double uu = f * 2.0 + lo;
  if (uu < lo) uu = lo;
  minv[tid] = 1.4142135623730951 * erfinv_d(uu);
}

__global__ void compute_u_kernel(const double2* Theta, const double2* Lamda,
                                 const float* rho, const float* tau, int it,
                                 double2* u) {
  int tid = blockIdx.x * blockDim.x + threadIdx.x;
  if (tid >= BATCH * MDIM) return;
  int b = tid / MDIM, kk = tid % MDIM;
  double r = (double)rho[it], t = (double)tau[it];
  const double2* Lb = Lamda + (size_t)b * NSQ;
  const double2* Tb = Theta + (size_t)b * NSQ;
  double ar = 0.0, ai = 0.0;
  for (int i = 0; i + kk < MDIM; ++i) {
    double2 L = Lb[i * NDIM + i + kk];
    double2 Th = Tb[i * NDIM + i + kk];
    ar += L.x + r * Th.x;
    ai += L.y + r * Th.y;
  }
  if (kk == 0) ar += -(t * 0.5) * (double)MDIM;
  double s = 1.0 / ((double)(MDIM - kk) * r);
  u[b * MDIM + kk] = make_double2(ar * s, ai * s);
}

// A32 = fp32(StackM - Lamda/r) ; U32 = I
__global__ void assemble_kernel(const double2* Theta, const double2* Lamda,
                                const double2* u, const float* Yre, const float* Yim,
                                const float* rho, const float* tau, int it,
                                float2* A32, float2* U32) {
  int tid = blockIdx.x * 256 + threadIdx.x;
  if (tid >= BATCH * NSQ) return;
  int b = tid / NSQ, rem = tid % NSQ, i = rem / NDIM, j = rem % NDIM;
  double r = (double)rho[it], t = (double)tau[it];
  size_t idx = (size_t)b * NSQ + rem;
  double2 L = Lamda[idx], Th = Theta[idx];
  double axr, axi;
  if (i < MDIM && j < MDIM) {
    int d = j - i;
    double2 uv = u[b * MDIM + (d >= 0 ? d : -d)];
    double uy = (d >= 0) ? uv.y : -uv.y;
    axr = uv.x - L.x / r;
    axi = uy - L.y / r;
  } else if (i < MDIM) {
    double yr = (double)Yre[(b * MDIM + i) * LDIM + (j - MDIM)];
    double yi = (double)Yim[(b * MDIM + i) * LDIM + (j - MDIM)];
    double inv = 1.0 / (1.0 + 2.0 * r);
    axr = (yr + 2.0 * L.x + 2.0 * r * Th.x) * inv - L.x / r;
    axi = (yi + 2.0 * L.y + 2.0 * r * Th.y) * inv - L.y / r;
  } else if (j < MDIM) {
    double yr = (double)Yre[(b * MDIM + j) * LDIM + (i - MDIM)];
    double yi = -(double)Yim[(b * MDIM + j) * LDIM + (i - MDIM)];
    double inv = 1.0 / (1.0 + 2.0 * r);
    axr = (yr + 2.0 * L.x + 2.0 * r * Th.x) * inv - L.x / r;
    axi = (yi + 2.0 * L.y + 2.0 * r * Th.y) * inv - L.y / r;
  } else {
    axr = Th.x - ((i == j) ? t / (2.0 * r) : 0.0);
    axi = Th.y;
  }
  A32[idx] = make_float2((float)axr, (float)axi);
  U32[idx] = make_float2((i == j) ? 1.0f : 0.0f, 0.0f);
}

__device__ __forceinline__ int pair_p(int j, int r) {
  return (j == 0) ? 0 : 1 + (j - 1 + r) % 127;
}
__device__ __forceinline__ int pair_q(int j, int r) {
  return 1 + (126 - j + r) % 127;
}

// One sweep (127 rounds) of fp32 Hermitian parallel-order Jacobi on A only.
// A LDS-resident (SoA, stride 129); records (br,bi) per pair per round.
// Fused rank/d1/d2 epilogue when last. 512 thr, one block per matrix.
__global__ __launch_bounds__(512) void jacobi_sweep_kernel(
    float2* __restrict__ A, float2* __restrict__ params,
    const double* __restrict__ minv, int it, int sweep, int last,
    double* __restrict__ d1, double* __restrict__ d2) {
  extern __shared__ float smem[];
  float* sAre = smem;             // 128 x 129
  float* sAim = smem + NDIM * RS; // 128 x 129
  __shared__ float sc[64], sbr[64], sbi[64];
  __shared__ int sp[64], sq[64];
  int b = blockIdx.x, tid = threadIdx.x;
  float2* Ag = A + (size_t)b * NSQ;
  float2* Pg = params + (size_t)b * (127 * 64);
  for (int i = tid; i < NSQ; i += 512) {
    float2 a = Ag[i];
    sAre[(i >> 7) * RS + (i & 127)] = a.x;
    sAim[(i >> 7) * RS + (i & 127)] = a.y;
  }
  __syncthreads();
  for (int r0 = 0; r0 < 127; ++r0) {
    int r = (sweep & 1) ? (126 - r0) : r0;
    if (tid < 64) {
      int p = pair_p(tid, r), q = pair_q(tid, r);
      sp[tid] = p; sq[tid] = q;
      float app = sAre[p * RS + p], aqq = sAre[q * RS + q];
      float gr = sAre[p * RS + q], gi = sAim[p * RS + q];
      float ag2 = gr * gr + gi * gi;
      float cc = 1.0f, br = 0.0f, bi = 0.0f;
      if (ag2 > 1e-24f) {
        float ag = sqrtf(ag2);
        float ta = (aqq - app) / (2.0f * ag);
        float tt = -copysignf(1.0f, ta) / (fabsf(ta) + sqrtf(1.0f + ta * ta));
        cc = 1.0f / sqrtf(1.0f + tt * tt);
        float tcag = tt * cc / ag;
        br = gr * tcag; bi = gi * tcag;
      }
      sc[tid] = cc; sbr[tid] = br; sbi[tid] = bi;
      Pg[r0 * 64 + tid] = make_float2(br, bi);   // cc = sqrt(1-br^2-bi^2)
    }
    __syncthreads();
    // Fused pass: pair-block (i,j): B <- L_i * B * R_j  (one LDS touch)
    {
      int j = tid & 63, i0 = tid >> 6;          // i0 in 0..7
      int pj = sp[j], qj = sq[j];
      float cj = sc[j], brj = sbr[j], bij = sbi[j];
#pragma unroll
      for (int k = 0; k < 8; ++k) {
        int i = i0 + 8 * k;
        int pi = sp[i], qi = sq[i];
        float ci = sc[i], bri = sbr[i], bii = sbi[i];
        int i00 = pi * RS + pj, i01 = pi * RS + qj;
        int i10 = qi * RS + pj, i11 = qi * RS + qj;
        float b00r = sAre[i00], b00i = sAim[i00];
        float b01r = sAre[i01], b01i = sAim[i01];
        float b10r = sAre[i10], b10i = sAim[i10];
        float b11r = sAre[i11], b11i = sAim[i11];
        float t00r = ci * b00r + (bri * b10r - bii * b10i);
        float t00i = ci * b00i + (bri * b10i + bii * b10r);
        float t01r = ci * b01r + (bri * b11r - bii * b11i);
        float t01i = ci * b01i + (bri * b11i + bii * b11r);
        float t10r = ci * b10r - (bri * b00r + bii * b00i);
        float t10i = ci * b10i - (bri * b00i - bii * b00r);
        float t11r = ci * b11r - (bri * b01r + bii * b01i);
        float t11i = ci * b11i - (bri * b01i - bii * b01r);
        sAre[i00] = cj * t00r + (brj * t01r + bij * t01i);
        sAim[i00] = cj * t00i + (brj * t01i - bij * t01r);
        sAre[i01] = cj * t01r - (brj * t00r - bij * t00i);
        sAim[i01] = cj * t01i - (brj * t00i + bij * t00r);
        sAre[i10] = cj * t10r + (brj * t11r + bij * t11i);
        sAim[i10] = cj * t10i + (brj * t11i - bij * t11r);
        sAre[i11] = cj * t11r - (brj * t10r - bij * t10i);
        sAim[i11] = cj * t11i - (brj * t10i + bij * t10r);
      }
    }
    __syncthreads();
  }
  for (int i = tid; i < NSQ; i += 512) {
    Ag[i] = make_float2(sAre[(i >> 7) * RS + (i & 127)],
                        sAim[(i >> 7) * RS + (i & 127)]);
  }
  if (last && tid < NDIM) {   // fused rankd (LDS stable since last barrier)
    float wj = sAre[tid * RS + tid];
    int rank = 0;
    for (int k2 = 0; k2 < NDIM; ++k2) {
      float wk = sAre[k2 * RS + k2];
      rank += (wk < wj) || (wk == wj && k2 < tid);
    }
    double mv = minv[(it * BATCH + b) * NDIM + rank];
    double v = (double)wj + mv;
    if (v < 0.0) v = 0.0;
    d1[b * NDIM + tid] = v;
    d2[b * NDIM + tid] = v - (double)wj;
  }
}

// Replay one sweep's rotations onto U = V^T. Each WAVE owns a 128x8 column
// chunk in LDS (SoA stride 9, conflict-free) -> ZERO barriers (same-wave
// LDS ops are in-order). 128 blocks x 512 thr (8 waves = 8 chunks; 2 blocks
// per matrix cover 16 chunks).
__global__ __launch_bounds__(512) void replay_kernel(
    float2* __restrict__ U, const float2* __restrict__ params, int sweep) {
  extern __shared__ float smem[];
  int tid = threadIdx.x, wv = tid >> 6, ln = tid & 63;
  int b = blockIdx.x >> 1, half = blockIdx.x & 1;
  int col0 = (half * 8 + wv) * 8;
  float* cre = smem + wv * (2 * NDIM * RCH);
  float* cim = cre + NDIM * RCH;
  float2* Ug = U + (size_t)b * NSQ;
  const float2* Pg = params + (size_t)b * (127 * 64);
  for (int e = ln; e < NDIM * 8; e += 64) {
    int row = e >> 3, c = e & 7;
    float2 v = Ug[row * NDIM + col0 + c];
    cre[row * RCH + c] = v.x;
    cim[row * RCH + c] = v.y;
  }
  for (int r0 = 0; r0 < 127; ++r0) {
    int r = (sweep & 1) ? (126 - r0) : r0;
    int p = pair_p(ln, r), q = pair_q(ln, r);
    float2 prm = Pg[r0 * 64 + ln];
    float br = prm.x, bi = prm.y;
    float cc = sqrtf(fmaxf(0.0f, 1.0f - br * br - bi * bi));
#pragma unroll
    for (int c = 0; c < 8; ++c) {
      int ip = p * RCH + c, iq = q * RCH + c;
      float upx = cre[ip], upy = cim[ip];
      float uqx = cre[iq], uqy = cim[iq];
      cre[ip] = cc * upx + (br * uqx + bi * uqy);   // U_p <- c U_p + conj(sb) U_q
      cim[ip] = cc * upy + (br * uqy - bi * uqx);
      cre[iq] = cc * uqx - (br * upx - bi * upy);   // U_q <- c U_q - sb U_p
      cim[iq] = cc * uqy - (br * upy + bi * upx);
    }
    __builtin_amdgcn_wave_barrier();   // pin compile-time order across rounds
  }
  for (int e = ln; e < NDIM * 8; e += 64) {
    int row = e >> 3, c = e & 7;
    Ug[row * NDIM + col0 + c] = make_float2(cre[row * RCH + c], cim[row * RCH + c]);
  }
}

// Theta = V diag(d1) V^H ; Lamda = (1-e/r) Lamda + e * V diag(d2) V^H.
// U = V^T in global; tiles loaded transposed+coalesced into SoA LDS.
__global__ __launch_bounds__(256) void update_kernel(
    const float2* U, const double* d1, const double* d2,
    const float* rho, const float* eta, int it,
    double2* Theta, double2* Lamda) {
  __shared__ float ViRe[32][33], ViIm[32][33];
  __shared__ float VkRe[32][33], VkIm[32][33];
  __shared__ double s1[32], s2[32];
  int blk = blockIdx.x;
  int b = blk >> 4, tile = blk & 15, ti = tile >> 2, tk = tile & 3;
  int tid = threadIdx.x;
  int lk = tid & 31, lig = tid >> 5;
  double r = (double)rho[it], e = (double)eta[it];
  double a1x[4] = {0, 0, 0, 0}, a1y[4] = {0, 0, 0, 0};
  double a2x[4] = {0, 0, 0, 0}, a2y[4] = {0, 0, 0, 0};
  const float2* Ub = U + (size_t)b * NSQ;
  for (int jc = 0; jc < 4; ++jc) {
    for (int e2 = tid; e2 < 1024; e2 += 256) {
      int rr = e2 & 31, cc2 = e2 >> 5;
      float2 v1 = Ub[(jc * 32 + cc2) * NDIM + ti * 32 + rr];
      ViRe[rr][cc2] = v1.x; ViIm[rr][cc2] = v1.y;
      float2 v2 = Ub[(jc * 32 + cc2) * NDIM + tk * 32 + rr];
      VkRe[rr][cc2] = v2.x; VkIm[rr][cc2] = v2.y;
    }
    if (tid < 32) {
      s1[tid] = d1[b * NDIM + jc * 32 + tid];
      s2[tid] = d2[b * NDIM + jc * 32 + tid];
    }
    __syncthreads();
#pragma unroll
    for (int uo = 0; uo < 4; ++uo) {
      int li = lig + uo * 8;
      double ax = a1x[uo], ay = a1y[uo], bx = a2x[uo], by = a2y[uo];
      for (int j = 0; j < 32; ++j) {
        float var = ViRe[li][j], vai = ViIm[li][j];
        float vbr = VkRe[lk][j], vbi = VkIm[lk][j];
        double pr = (double)(var * vbr + vai * vbi);
        double pi = (double)(vai * vbr - var * vbi);
        ax += s1[j] * pr; ay += s1[j] * pi;
        bx += s2[j] * pr; by += s2[j] * pi;
      }
      a1x[uo] = ax; a1y[uo] = ay; a2x[uo] = bx; a2y[uo] = by;
    }
    __syncthreads();
  }
  double lf = 1.0 - e / r;
#pragma unroll
  for (int uo = 0; uo < 4; ++uo) {
    int gi = ti * 32 + lig + uo * 8, gk = tk * 32 + lk;
    size_t idx = (size_t)b * NSQ + gi * NDIM + gk;
    Theta[idx] = make_double2(a1x[uo], a1y[uo]);
    double2 Lold = Lamda[idx];
    Lamda[idx] = make_double2(lf * Lold.x + e * a2x[uo], lf * Lold.y + e * a2y[uo]);
  }
}

// OUTPUT (float32 real parts): T[i][j] = u[|i-j|].re ; uvec.re = u.re
__global__ void writeout_kernel(const double2* u, float* out) {
  int tid = blockIdx.x * 256 + threadIdx.x;
  if (tid >= OUT_ELEMS) return;
  double re;
  if (tid < BATCH * MDIM * MDIM) {
    int b = tid >> 12, rem = tid & 4095, i = rem >> 6, j = rem & 63;
    int d = j - i;
    re = u[b * MDIM + (d >= 0 ? d : -d)].x;
  } else {
    int k2 = tid - BATCH * MDIM * MDIM;
    int b = k2 >> 6, kk = k2 & 63;
    re = u[b * MDIM + kk].x;
  }
  out[tid] = (float)re;
}

// ------------------------------- launch ------------------------------------
extern "C" void kernel_launch(void* const* d_in, const int* in_sizes, int n_in,
                              void* d_out, int out_size, void* d_ws, size_t ws_size,
                              hipStream_t stream) {
  const float* Yre = (const float*)d_in[0];
  const float* Yim = (const float*)d_in[1];
  const float* rho = (const float*)d_in[2];
  const float* tau = (const float*)d_in[3];
  const float* eta = (const float*)d_in[4];
  float* out = (float*)d_out;

  char* ws = (char*)d_ws;
  size_t off = 0;
  auto take = [&](size_t bytes) -> char* {
    char* p = ws + off;
    off += (bytes + 255) & ~(size_t)255;
    return p;
  };
  double2* u     = (double2*)take((size_t)BATCH * MDIM * sizeof(double2));
  double*  minv  = (double*)take((size_t)KITER * BATCH * NDIM * sizeof(double));
  double*  d1    = (double*)take((size_t)BATCH * NDIM * sizeof(double));
  double*  d2    = (double*)take((size_t)BATCH * NDIM * sizeof(double));
  double2* Lamda = (double2*)take((size_t)BATCH * NSQ * sizeof(double2));  // 16.8 MB
  double2* Theta = (double2*)take((size_t)BATCH * NSQ * sizeof(double2));  // 16.8 MB
  float2*  A32   = (float2*)take((size_t)BATCH * NSQ * sizeof(float2));    //  8.4 MB
  float2*  U32   = (float2*)take((size_t)BATCH * NSQ * sizeof(float2));    //  8.4 MB
  float2*  prm   = (float2*)take((size_t)BATCH * 127 * 64 * sizeof(float2)); // 4.2 MB
  (void)in_sizes; (void)n_in; (void)ws_size; (void)out_size;  // ~55.5 MB total

  hipFuncSetAttribute((const void*)jacobi_sweep_kernel,
                      hipFuncAttributeMaxDynamicSharedMemorySize, JAC_LDS_BYTES);
  hipFuncSetAttribute((const void*)replay_kernel,
                      hipFuncAttributeMaxDynamicSharedMemorySize, REP_LDS_BYTES);

  zero_kernel<<<2048, 256, 0, stream>>>((double*)Theta, (size_t)BATCH * NSQ * 2);
  zero_kernel<<<2048, 256, 0, stream>>>((double*)Lamda, (size_t)BATCH * NSQ * 2);
  prng_kernel<<<(KITER * BATCH * NDIM + 255) / 256, 256, 0, stream>>>(minv);

  for (int it = 0; it < KITER - 1; ++it) {
    compute_u_kernel<<<16, 256, 0, stream>>>(Theta, Lamda, rho, tau, it, u);
    assemble_kernel<<<BATCH * NSQ / 256, 256, 0, stream>>>(Theta, Lamda, u, Yre, Yim,
                                                           rho, tau, it, A32, U32);
    for (int s = 0; s < SWEEPS; ++s) {
      jacobi_sweep_kernel<<<BATCH, 512, JAC_LDS_BYTES, stream>>>(
          A32, prm, minv, it, s, (s == SWEEPS - 1) ? 1 : 0, d1, d2);
      replay_kernel<<<BATCH * 2, 512, REP_LDS_BYTES, stream>>>(U32, prm, s);
    }
    update_kernel<<<BATCH * 16, 256, 0, stream>>>(U32, d1, d2, rho, eta, it, Theta, Lamda);
  }
  compute_u_kernel<<<16, 256, 0, stream>>>(Theta, Lamda, rho, tau, KITER - 1, u);
  writeout_kernel<<<(OUT_ELEMS + 255) / 256, 256, 0, stream>>>(u, out);
}

// Round 10
// 23872.868 us; speedup vs baseline: 18.0420x; 1.2863x over previous
//
#include <hip/hip_runtime.h>
#include <stdint.h>

// ---------------------------------------------------------------------------
// AnmNetwork: ADMM-like complex PSD iteration. B=64, m=l=64, n=128, K=10.
//  * Sita = V relu(w + minv[rank]) V^H  (second eigh mathematically redundant)
//  * Lamda_new = (1 - eta/rho) Lamda + eta * V diag(relu(w+m)-w) V^H
//  * Output depends only on state entering iteration K-1 -> 9 eigh rounds.
//  * PRNG: JAX threefry2x32 partitionable counters (bit-exact, R5).
// R10 (replay was ~7ms of dead serial time; jacobi rounds stall-bound):
//  * combined_kernel: blocks 0-63 = jacobi sweep s (1 block/matrix, 132KB
//    LDS), blocks 64-191 = replay of sweep s-1 onto U on otherwise-idle CUs.
//    Param double-buffer ping-pong; visibility via dispatch boundaries.
//  * jacobi fused pass batches all 8 pair-blocks: 64 ds_read burst -> VALU
//    -> 64 ds_write burst (register arrays) to hide LDS dependency stalls.
// State (Theta/Lamda), PRNG, u, writeout stay fp64. SWEEPS=7 (absmax 0.084).
// ---------------------------------------------------------------------------

#define BATCH 64
#define MDIM 64
#define LDIM 64
#define NDIM 128
#define NSQ (NDIM * NDIM)
#define KITER 10
#define SWEEPS 7
#define RS 129                                  // jacobi LDS row stride (floats)
#define JAC_LDS_BYTES (2 * NDIM * RS * (int)sizeof(float))   // 132,096 B
#define RCH 9                                   // replay chunk col stride
#define OUT_ELEMS 266240   // 64*64*64 (T) + 64*64 (uvec), f32 real parts

// ----------------------------- threefry2x32 --------------------------------
__device__ __forceinline__ void tf_block(unsigned k0, unsigned k1,
                                         unsigned& x0, unsigned& x1) {
  unsigned k2 = k0 ^ k1 ^ 0x1BD11BDAu;
  x0 += k0; x1 += k1;
#define TF_R(r) { x0 += x1; x1 = (x1 << (r)) | (x1 >> (32 - (r))); x1 ^= x0; }
  TF_R(13) TF_R(15) TF_R(26) TF_R(6)
  x0 += k1; x1 += k2 + 1u;
  TF_R(17) TF_R(29) TF_R(16) TF_R(24)
  x0 += k2; x1 += k0 + 2u;
  TF_R(13) TF_R(15) TF_R(26) TF_R(6)
  x0 += k0; x1 += k1 + 3u;
  TF_R(17) TF_R(29) TF_R(16) TF_R(24)
  x0 += k1; x1 += k2 + 4u;
  TF_R(13) TF_R(15) TF_R(26) TF_R(6)
  x0 += k2; x1 += k0 + 5u;
#undef TF_R
}

// ------------------------------- erfinv (f64) ------------------------------
__device__ double erfinv_d(double x) {
  double w = -log1p(-x * x);
  double p;
  if (w < 6.25) {
    w -= 3.125;
    const double c[23] = {
      -3.6444120640178196996e-21, -1.685059138182016589e-19,
      1.2858480715256400167e-18,  1.115787767802518096e-17,
      -1.333171662854620906e-16,  2.0972767875968561637e-17,
      6.6376381343583238325e-15,  -4.0545662729752068639e-14,
      -8.1519341976054721522e-14, 2.6335093153082322977e-12,
      -1.2975133253453532498e-11, -5.4154120542946279317e-11,
      1.051212273321532285e-09,   -4.1126339803469836976e-09,
      -2.9070369957882005086e-08, 4.2347877827932403518e-07,
      -1.3654692000834678645e-06, -1.3882523362786468719e-05,
      1.8673420803405714802e-04,  -7.4070253416626697512e-04,
      -6.0336708714301490533e-03, 2.4015818242558961693e-01,
      1.6536545626831027356e+00};
    p = c[0];
#pragma unroll
    for (int i = 1; i < 23; ++i) p = p * w + c[i];
  } else if (w < 16.0) {
    double s = sqrt(w) - 3.25;
    const double c[19] = {
      2.2137376921775787049e-09,  9.0756561938885390979e-08,
      -2.7517406297064545428e-07, 1.8239629214389227755e-08,
      1.5027403968909827627e-06,  -4.013867526981545969e-06,
      2.9234449089955446044e-06,  1.2475304481671778723e-05,
      -4.7318229009055733981e-05, 6.8284851459573175448e-05,
      2.4031110387097893999e-05,  -3.5503752036284748449e-04,
      9.5328937973738049703e-04,  -1.6882755560235047313e-03,
      2.4914420961078508066e-03,  -3.7512085075692412107e-03,
      5.3709145535900636051e-03,  1.0052589676941592334e+00,
      3.0838856104922207635e+00};
    p = c[0];
#pragma unroll
    for (int i = 1; i < 19; ++i) p = p * s + c[i];
  } else {
    double s = sqrt(w) - 5.0;
    const double c[17] = {
      -2.7109920616438573243e-11, -2.5556418169965252055e-10,
      1.5076572693500548083e-09,  -3.7894654401267369937e-09,
      7.6157012080783393804e-09,  -1.4960026627149240478e-08,
      2.9147953450901080826e-08,  -6.7711997758452339498e-08,
      2.2900482228026654717e-07,  -9.9298272942317002539e-07,
      4.5260625972231537039e-06,  -1.9681778105531670567e-05,
      7.5995277030017761139e-05,  -2.1503011930044477347e-04,
      -1.3871931833623122026e-04, 1.0103004648645343977e+00,
      4.8499064014085844221e+00};
    p = c[0];
#pragma unroll
    for (int i = 1; i < 17; ++i) p = p * s + c[i];
  }
  double z = p * x;
  const double spi2 = 0.8862269254527580;  // sqrt(pi)/2
  double ax = fabs(x);
#pragma unroll
  for (int nr = 0; nr < 2; ++nr) {
    if (ax > 0.9375) {
      double az = fabs(z);
      double corr = (erfc(az) - (1.0 - ax)) * spi2 * exp(az * az);
      az += corr;
      z = copysign(az, x);
    } else {
      z -= (erf(z) - x) * spi2 * exp(z * z);
    }
  }
  return z;
}

// ------------------------------- kernels -----------------------------------
__global__ void zero_kernel(double* p, size_t n) {
  size_t i = (size_t)blockIdx.x * blockDim.x + threadIdx.x;
  size_t stride = (size_t)gridDim.x * blockDim.x;
  for (; i < n; i += stride) p[i] = 0.0;
}

__global__ void prng_kernel(double* minv) {
  int tid = blockIdx.x * blockDim.x + threadIdx.x;
  if (tid >= KITER * BATCH * NDIM) return;
  int it = tid / (BATCH * NDIM);
  int i = tid % (BATCH * NDIM);
  unsigned nk0 = 0u, nk1 = (unsigned)it;
  tf_block(0u, 42u, nk0, nk1);                       // fold_in
  unsigned c0 = 0u, c1 = (unsigned)i;                // partitionable counter
  tf_block(nk0, nk1, c0, c1);
  unsigned long long bits = ((unsigned long long)c0 << 32) | (unsigned long long)c1;
  unsigned long long fb = (bits >> 12) | 0x3FF0000000000000ull;
  double f = __builtin_bit_cast(double, fb) - 1.0;
  const double lo = __builtin_bit_cast(double, 0xBFEFFFFFFFFFFFFFull);
  double uu = f * 2.0 + lo;
  if (uu < lo) uu = lo;
  minv[tid] = 1.4142135623730951 * erfinv_d(uu);
}

__global__ void compute_u_kernel(const double2* Theta, const double2* Lamda,
                                 const float* rho, const float* tau, int it,
                                 double2* u) {
  int tid = blockIdx.x * blockDim.x + threadIdx.x;
  if (tid >= BATCH * MDIM) return;
  int b = tid / MDIM, kk = tid % MDIM;
  double r = (double)rho[it], t = (double)tau[it];
  const double2* Lb = Lamda + (size_t)b * NSQ;
  const double2* Tb = Theta + (size_t)b * NSQ;
  double ar = 0.0, ai = 0.0;
  for (int i = 0; i + kk < MDIM; ++i) {
    double2 L = Lb[i * NDIM + i + kk];
    double2 Th = Tb[i * NDIM + i + kk];
    ar += L.x + r * Th.x;
    ai += L.y + r * Th.y;
  }
  if (kk == 0) ar += -(t * 0.5) * (double)MDIM;
  double s = 1.0 / ((double)(MDIM - kk) * r);
  u[b * MDIM + kk] = make_double2(ar * s, ai * s);
}

// A32 = fp32(StackM - Lamda/r) ; U32 = I
__global__ void assemble_kernel(const double2* Theta, const double2* Lamda,
                                const double2* u, const float* Yre, const float* Yim,
                                const float* rho, const float* tau, int it,
                                float2* A32, float2* U32) {
  int tid = blockIdx.x * 256 + threadIdx.x;
  if (tid >= BATCH * NSQ) return;
  int b = tid / NSQ, rem = tid % NSQ, i = rem / NDIM, j = rem % NDIM;
  double r = (double)rho[it], t = (double)tau[it];
  size_t idx = (size_t)b * NSQ + rem;
  double2 L = Lamda[idx], Th = Theta[idx];
  double axr, axi;
  if (i < MDIM && j < MDIM) {
    int d = j - i;
    double2 uv = u[b * MDIM + (d >= 0 ? d : -d)];
    double uy = (d >= 0) ? uv.y : -uv.y;
    axr = uv.x - L.x / r;
    axi = uy - L.y / r;
  } else if (i < MDIM) {
    double yr = (double)Yre[(b * MDIM + i) * LDIM + (j - MDIM)];
    double yi = (double)Yim[(b * MDIM + i) * LDIM + (j - MDIM)];
    double inv = 1.0 / (1.0 + 2.0 * r);
    axr = (yr + 2.0 * L.x + 2.0 * r * Th.x) * inv - L.x / r;
    axi = (yi + 2.0 * L.y + 2.0 * r * Th.y) * inv - L.y / r;
  } else if (j < MDIM) {
    double yr = (double)Yre[(b * MDIM + j) * LDIM + (i - MDIM)];
    double yi = -(double)Yim[(b * MDIM + j) * LDIM + (i - MDIM)];
    double inv = 1.0 / (1.0 + 2.0 * r);
    axr = (yr + 2.0 * L.x + 2.0 * r * Th.x) * inv - L.x / r;
    axi = (yi + 2.0 * L.y + 2.0 * r * Th.y) * inv - L.y / r;
  } else {
    axr = Th.x - ((i == j) ? t / (2.0 * r) : 0.0);
    axi = Th.y;
  }
  A32[idx] = make_float2((float)axr, (float)axi);
  U32[idx] = make_float2((i == j) ? 1.0f : 0.0f, 0.0f);
}

__device__ __forceinline__ int pair_p(int j, int r) {
  return (j == 0) ? 0 : 1 + (j - 1 + r) % 127;
}
__device__ __forceinline__ int pair_q(int j, int r) {
  return 1 + (126 - j + r) % 127;
}

// Replay device body: wave-owned 128x8 U column chunk in LDS, zero barriers.
__device__ void replay_body(float* smem, float2* __restrict__ U,
                            const float2* __restrict__ params,
                            int rb, int sweep) {
  int tid = threadIdx.x, wv = tid >> 6, ln = tid & 63;
  int b = rb >> 1, half = rb & 1;
  int col0 = (half * 8 + wv) * 8;
  float* cre = smem + wv * (2 * NDIM * RCH);
  float* cim = cre + NDIM * RCH;
  float2* Ug = U + (size_t)b * NSQ;
  const float2* Pg = params + (size_t)b * (127 * 64);
  for (int e = ln; e < NDIM * 8; e += 64) {
    int row = e >> 3, c = e & 7;
    float2 v = Ug[row * NDIM + col0 + c];
    cre[row * RCH + c] = v.x;
    cim[row * RCH + c] = v.y;
  }
  for (int r0 = 0; r0 < 127; ++r0) {
    int r = (sweep & 1) ? (126 - r0) : r0;
    int p = pair_p(ln, r), q = pair_q(ln, r);
    float2 prm = Pg[r0 * 64 + ln];
    float br = prm.x, bi = prm.y;
    float cc = sqrtf(fmaxf(0.0f, 1.0f - br * br - bi * bi));
#pragma unroll
    for (int c = 0; c < 8; ++c) {
      int ip = p * RCH + c, iq = q * RCH + c;
      float upx = cre[ip], upy = cim[ip];
      float uqx = cre[iq], uqy = cim[iq];
      cre[ip] = cc * upx + (br * uqx + bi * uqy);   // U_p <- c U_p + conj(sb) U_q
      cim[ip] = cc * upy + (br * uqy - bi * uqx);
      cre[iq] = cc * uqx - (br * upx - bi * upy);   // U_q <- c U_q - sb U_p
      cim[iq] = cc * uqy - (br * upy + bi * upx);
    }
    __builtin_amdgcn_wave_barrier();
  }
  for (int e = ln; e < NDIM * 8; e += 64) {
    int row = e >> 3, c = e & 7;
    Ug[row * NDIM + col0 + c] = make_float2(cre[row * RCH + c], cim[row * RCH + c]);
  }
}

// Combined dispatch: blocks 0..63 jacobi sweep `sweep` (params -> prmW);
// blocks 64..191 replay sweep-1 from prmR onto U (idle CUs).
__global__ __launch_bounds__(512) void combined_kernel(
    float2* __restrict__ A, float2* __restrict__ U,
    float2* __restrict__ prmW, const float2* __restrict__ prmR,
    const double* __restrict__ minv, int it, int sweep, int last,
    double* __restrict__ d1, double* __restrict__ d2) {
  extern __shared__ float smem[];
  if (blockIdx.x >= BATCH) {
    if (sweep > 0) replay_body(smem, U, prmR, blockIdx.x - BATCH, sweep - 1);
    return;
  }
  float* sAre = smem;             // 128 x 129
  float* sAim = smem + NDIM * RS; // 128 x 129
  __shared__ float sc[64], sbr[64], sbi[64];
  __shared__ int sp[64], sq[64];
  int b = blockIdx.x, tid = threadIdx.x;
  float2* Ag = A + (size_t)b * NSQ;
  float2* Pg = prmW + (size_t)b * (127 * 64);
  for (int i = tid; i < NSQ; i += 512) {
    float2 a = Ag[i];
    sAre[(i >> 7) * RS + (i & 127)] = a.x;
    sAim[(i >> 7) * RS + (i & 127)] = a.y;
  }
  __syncthreads();
  for (int r0 = 0; r0 < 127; ++r0) {
    int r = (sweep & 1) ? (126 - r0) : r0;
    if (tid < 64) {
      int p = pair_p(tid, r), q = pair_q(tid, r);
      sp[tid] = p; sq[tid] = q;
      float app = sAre[p * RS + p], aqq = sAre[q * RS + q];
      float gr = sAre[p * RS + q], gi = sAim[p * RS + q];
      float ag2 = gr * gr + gi * gi;
      float cc = 1.0f, br = 0.0f, bi = 0.0f;
      if (ag2 > 1e-24f) {
        float ag = sqrtf(ag2);
        float ta = (aqq - app) / (2.0f * ag);
        float tt = -copysignf(1.0f, ta) / (fabsf(ta) + sqrtf(1.0f + ta * ta));
        cc = 1.0f / sqrtf(1.0f + tt * tt);
        float tcag = tt * cc / ag;
        br = gr * tcag; bi = gi * tcag;
      }
      sc[tid] = cc; sbr[tid] = br; sbi[tid] = bi;
      Pg[r0 * 64 + tid] = make_float2(br, bi);   // cc = sqrt(1-br^2-bi^2)
    }
    __syncthreads();
    // Fused pass, batched: 64-read burst -> VALU -> 64-write burst.
    {
      int j = tid & 63, i0 = tid >> 6;
      int pj = sp[j], qj = sq[j];
      float cj = sc[j], brj = sbr[j], bij = sbi[j];
      int bp[8], bq[8];
      float ci[8], bri[8], bii[8];
      float R[8][8];
#pragma unroll
      for (int k = 0; k < 8; ++k) {
        int i = i0 + 8 * k;
        bp[k] = sp[i] * RS; bq[k] = sq[i] * RS;
        ci[k] = sc[i]; bri[k] = sbr[i]; bii[k] = sbi[i];
      }
#pragma unroll
      for (int k = 0; k < 8; ++k) {
        R[k][0] = sAre[bp[k] + pj]; R[k][1] = sAim[bp[k] + pj];
        R[k][2] = sAre[bp[k] + qj]; R[k][3] = sAim[bp[k] + qj];
        R[k][4] = sAre[bq[k] + pj]; R[k][5] = sAim[bq[k] + pj];
        R[k][6] = sAre[bq[k] + qj]; R[k][7] = sAim[bq[k] + qj];
      }
#pragma unroll
      for (int k = 0; k < 8; ++k) {
        float b00r = R[k][0], b00i = R[k][1], b01r = R[k][2], b01i = R[k][3];
        float b10r = R[k][4], b10i = R[k][5], b11r = R[k][6], b11i = R[k][7];
        float t00r = ci[k] * b00r + (bri[k] * b10r - bii[k] * b10i);
        float t00i = ci[k] * b00i + (bri[k] * b10i + bii[k] * b10r);
        float t01r = ci[k] * b01r + (bri[k] * b11r - bii[k] * b11i);
        float t01i = ci[k] * b01i + (bri[k] * b11i + bii[k] * b11r);
        float t10r = ci[k] * b10r - (bri[k] * b00r + bii[k] * b00i);
        float t10i = ci[k] * b10i - (bri[k] * b00i - bii[k] * b00r);
        float t11r = ci[k] * b11r - (bri[k] * b01r + bii[k] * b01i);
        float t11i = ci[k] * b11i - (bri[k] * b01i - bii[k] * b01r);
        R[k][0] = cj * t00r + (brj * t01r + bij * t01i);
        R[k][1] = cj * t00i + (brj * t01i - bij * t01r);
        R[k][2] = cj * t01r - (brj * t00r - bij * t00i);
        R[k][3] = cj * t01i - (brj * t00i + bij * t00r);
        R[k][4] = cj * t10r + (brj * t11r + bij * t11i);
        R[k][5] = cj * t10i + (brj * t11i - bij * t11r);
        R[k][6] = cj * t11r - (brj * t10r - bij * t10i);
        R[k][7] = cj * t11i - (brj * t10i + bij * t10r);
      }
#pragma unroll
      for (int k = 0; k < 8; ++k) {
        sAre[bp[k] + pj] = R[k][0]; sAim[bp[k] + pj] = R[k][1];
        sAre[bp[k] + qj] = R[k][2]; sAim[bp[k] + qj] = R[k][3];
        sAre[bq[k] + pj] = R[k][4]; sAim[bq[k] + pj] = R[k][5];
        sAre[bq[k] + qj] = R[k][6]; sAim[bq[k] + qj] = R[k][7];
      }
    }
    __syncthreads();
  }
  for (int i = tid; i < NSQ; i += 512) {
    Ag[i] = make_float2(sAre[(i >> 7) * RS + (i & 127)],
                        sAim[(i >> 7) * RS + (i & 127)]);
  }
  if (last && tid < NDIM) {   // fused rankd
    float wj = sAre[tid * RS + tid];
    int rank = 0;
    for (int k2 = 0; k2 < NDIM; ++k2) {
      float wk = sAre[k2 * RS + k2];
      rank += (wk < wj) || (wk == wj && k2 < tid);
    }
    double mv = minv[(it * BATCH + b) * NDIM + rank];
    double v = (double)wj + mv;
    if (v < 0.0) v = 0.0;
    d1[b * NDIM + tid] = v;
    d2[b * NDIM + tid] = v - (double)wj;
  }
}

// Final replay of the last sweep (before update_kernel).
__global__ __launch_bounds__(512) void replay_kernel(
    float2* __restrict__ U, const float2* __restrict__ params, int sweep) {
  extern __shared__ float smem[];
  replay_body(smem, U, params, blockIdx.x, sweep);
}

// Theta = V diag(d1) V^H ; Lamda = (1-e/r) Lamda + e * V diag(d2) V^H.
__global__ __launch_bounds__(256) void update_kernel(
    const float2* U, const double* d1, const double* d2,
    const float* rho, const float* eta, int it,
    double2* Theta, double2* Lamda) {
  __shared__ float ViRe[32][33], ViIm[32][33];
  __shared__ float VkRe[32][33], VkIm[32][33];
  __shared__ double s1[32], s2[32];
  int blk = blockIdx.x;
  int b = blk >> 4, tile = blk & 15, ti = tile >> 2, tk = tile & 3;
  int tid = threadIdx.x;
  int lk = tid & 31, lig = tid >> 5;
  double r = (double)rho[it], e = (double)eta[it];
  double a1x[4] = {0, 0, 0, 0}, a1y[4] = {0, 0, 0, 0};
  double a2x[4] = {0, 0, 0, 0}, a2y[4] = {0, 0, 0, 0};
  const float2* Ub = U + (size_t)b * NSQ;
  for (int jc = 0; jc < 4; ++jc) {
    for (int e2 = tid; e2 < 1024; e2 += 256) {
      int rr = e2 & 31, cc2 = e2 >> 5;
      float2 v1 = Ub[(jc * 32 + cc2) * NDIM + ti * 32 + rr];
      ViRe[rr][cc2] = v1.x; ViIm[rr][cc2] = v1.y;
      float2 v2 = Ub[(jc * 32 + cc2) * NDIM + tk * 32 + rr];
      VkRe[rr][cc2] = v2.x; VkIm[rr][cc2] = v2.y;
    }
    if (tid < 32) {
      s1[tid] = d1[b * NDIM + jc * 32 + tid];
      s2[tid] = d2[b * NDIM + jc * 32 + tid];
    }
    __syncthreads();
#pragma unroll
    for (int uo = 0; uo < 4; ++uo) {
      int li = lig + uo * 8;
      double ax = a1x[uo], ay = a1y[uo], bx = a2x[uo], by = a2y[uo];
      for (int j = 0; j < 32; ++j) {
        float var = ViRe[li][j], vai = ViIm[li][j];
        float vbr = VkRe[lk][j], vbi = VkIm[lk][j];
        double pr = (double)(var * vbr + vai * vbi);
        double pi = (double)(vai * vbr - var * vbi);
        ax += s1[j] * pr; ay += s1[j] * pi;
        bx += s2[j] * pr; by += s2[j] * pi;
      }
      a1x[uo] = ax; a1y[uo] = ay; a2x[uo] = bx; a2y[uo] = by;
    }
    __syncthreads();
  }
  double lf = 1.0 - e / r;
#pragma unroll
  for (int uo = 0; uo < 4; ++uo) {
    int gi = ti * 32 + lig + uo * 8, gk = tk * 32 + lk;
    size_t idx = (size_t)b * NSQ + gi * NDIM + gk;
    Theta[idx] = make_double2(a1x[uo], a1y[uo]);
    double2 Lold = Lamda[idx];
    Lamda[idx] = make_double2(lf * Lold.x + e * a2x[uo], lf * Lold.y + e * a2y[uo]);
  }
}

// OUTPUT (float32 real parts): T[i][j] = u[|i-j|].re ; uvec.re = u.re
__global__ void writeout_kernel(const double2* u, float* out) {
  int tid = blockIdx.x * 256 + threadIdx.x;
  if (tid >= OUT_ELEMS) return;
  double re;
  if (tid < BATCH * MDIM * MDIM) {
    int b = tid >> 12, rem = tid & 4095, i = rem >> 6, j = rem & 63;
    int d = j - i;
    re = u[b * MDIM + (d >= 0 ? d : -d)].x;
  } else {
    int k2 = tid - BATCH * MDIM * MDIM;
    int b = k2 >> 6, kk = k2 & 63;
    re = u[b * MDIM + kk].x;
  }
  out[tid] = (float)re;
}

// ------------------------------- launch ------------------------------------
extern "C" void kernel_launch(void* const* d_in, const int* in_sizes, int n_in,
                              void* d_out, int out_size, void* d_ws, size_t ws_size,
                              hipStream_t stream) {
  const float* Yre = (const float*)d_in[0];
  const float* Yim = (const float*)d_in[1];
  const float* rho = (const float*)d_in[2];
  const float* tau = (const float*)d_in[3];
  const float* eta = (const float*)d_in[4];
  float* out = (float*)d_out;

  char* ws = (char*)d_ws;
  size_t off = 0;
  auto take = [&](size_t bytes) -> char* {
    char* p = ws + off;
    off += (bytes + 255) & ~(size_t)255;
    return p;
  };
  double2* u     = (double2*)take((size_t)BATCH * MDIM * sizeof(double2));
  double*  minv  = (double*)take((size_t)KITER * BATCH * NDIM * sizeof(double));
  double*  d1    = (double*)take((size_t)BATCH * NDIM * sizeof(double));
  double*  d2    = (double*)take((size_t)BATCH * NDIM * sizeof(double));
  double2* Lamda = (double2*)take((size_t)BATCH * NSQ * sizeof(double2));  // 16.8 MB
  double2* Theta = (double2*)take((size_t)BATCH * NSQ * sizeof(double2));  // 16.8 MB
  float2*  A32   = (float2*)take((size_t)BATCH * NSQ * sizeof(float2));    //  8.4 MB
  float2*  U32   = (float2*)take((size_t)BATCH * NSQ * sizeof(float2));    //  8.4 MB
  float2*  prm0  = (float2*)take((size_t)BATCH * 127 * 64 * sizeof(float2)); // 4.2 MB
  float2*  prm1  = (float2*)take((size_t)BATCH * 127 * 64 * sizeof(float2)); // 4.2 MB
  float2*  prmB[2] = {prm0, prm1};
  (void)in_sizes; (void)n_in; (void)ws_size; (void)out_size;  // ~59.7 MB total

  hipFuncSetAttribute((const void*)combined_kernel,
                      hipFuncAttributeMaxDynamicSharedMemorySize, JAC_LDS_BYTES);
  hipFuncSetAttribute((const void*)replay_kernel,
                      hipFuncAttributeMaxDynamicSharedMemorySize, JAC_LDS_BYTES);

  zero_kernel<<<2048, 256, 0, stream>>>((double*)Theta, (size_t)BATCH * NSQ * 2);
  zero_kernel<<<2048, 256, 0, stream>>>((double*)Lamda, (size_t)BATCH * NSQ * 2);
  prng_kernel<<<(KITER * BATCH * NDIM + 255) / 256, 256, 0, stream>>>(minv);

  for (int it = 0; it < KITER - 1; ++it) {
    compute_u_kernel<<<16, 256, 0, stream>>>(Theta, Lamda, rho, tau, it, u);
    assemble_kernel<<<BATCH * NSQ / 256, 256, 0, stream>>>(Theta, Lamda, u, Yre, Yim,
                                                           rho, tau, it, A32, U32);
    for (int s = 0; s < SWEEPS; ++s) {
      // blocks 0..63: jacobi sweep s -> prm[s&1]; blocks 64..191: replay s-1
      combined_kernel<<<BATCH + 2 * BATCH, 512, JAC_LDS_BYTES, stream>>>(
          A32, U32, prmB[s & 1], prmB[(s + 1) & 1], minv, it, s,
          (s == SWEEPS - 1) ? 1 : 0, d1, d2);
    }
    replay_kernel<<<2 * BATCH, 512, JAC_LDS_BYTES, stream>>>(
        U32, prmB[(SWEEPS - 1) & 1], SWEEPS - 1);
    update_kernel<<<BATCH * 16, 256, 0, stream>>>(U32, d1, d2, rho, eta, it, Theta, Lamda);
  }
  compute_u_kernel<<<16, 256, 0, stream>>>(Theta, Lamda, rho, tau, KITER - 1, u);
  writeout_kernel<<<(OUT_ELEMS + 255) / 256, 256, 0, stream>>>(u, out);
}